// Round 8
// baseline (350.523 us; speedup 1.0000x reference)
//
#include <hip/hip_runtime.h>

#define N_NODES 50000
#define N_EDGES 800000
#define ET (N_EDGES + N_NODES)   // 850000 incl. self loops
#define HEADS 8
#define NPAD 50048               // 782 blocks * 64 nodes
#define SCAN_NB 196              // ceil(50000/256)
#define CAP 96                   // LDS-cached edges per node (deg>CAP -> recompute)
#define LRS 1032                 // LDS A-tile row stride (halves, 16B-aligned)
#define NB_DEG 3321              // ceil(850000/256)
#define NB_GEMM1 782             // NPAD/64

typedef __attribute__((ext_vector_type(8))) _Float16 half8;
typedef __attribute__((ext_vector_type(2))) _Float16 half2v;
typedef __attribute__((ext_vector_type(4))) float f32x4;

// wave-local LDS fence: drains this wave's outstanding DS ops (same-wave
// cross-lane LDS write->read; consumers are ds_reads, ordered by "memory").
__device__ __forceinline__ void wave_lds_fence(){
  asm volatile("s_waitcnt lgkmcnt(0)" ::: "memory");
}

__device__ __forceinline__ int edge_src(const int* ei, int e, int is64){
  if (e >= N_EDGES) return e - N_EDGES;          // self loop
  return is64 ? ei[2*e] : ei[e];
}
__device__ __forceinline__ int edge_dst(const int* ei, int e, int is64){
  if (e >= N_EDGES) return e - N_EDGES;          // self loop
  return is64 ? ei[2*(N_EDGES + e)] : ei[N_EDGES + e];
}

// ======== launch 1: init (zero deg/cnt + layout probe) FUSED with wprep ========
// blocks [0,196): init; [196,452): W2 pack; [452,516): W1 pack; [516,520): wtilde
__global__ void k_init_wprep(const int* __restrict__ ei, int* __restrict__ deg,
                             int* __restrict__ cnt, int* __restrict__ flag,
                             const float* __restrict__ W1, const float* __restrict__ W2,
                             const float* __restrict__ as2, const float* __restrict__ ad2,
                             _Float16* __restrict__ Bp1, _Float16* __restrict__ Bp,
                             float* __restrict__ ws2, float* __restrict__ wd2){
  int b = blockIdx.x;
  int t_ = threadIdx.x;
  if (b < SCAN_NB){
    int i = b*256 + t_;
    if (i < N_NODES){ deg[i] = 0; cnt[i] = 0; }
    if (i == 0){
      int zeros = 0;
      for (int k = 0; k < 64; k++){
        if (ei[2*k + 1] == 0) zeros++;
      }
      *flag = (zeros >= 60) ? 1 : 0;   // 1 => int64 little-endian layout
    }
  } else if (b < SCAN_NB + 256){
    int t = (b - SCAN_NB)*256 + t_;
    int j = t & 7, lane = (t >> 3) & 63, nt = (t >> 9) & 3, kt = t >> 11;
    int k = kt*32 + (lane >> 4)*8 + j;
    int c = nt*16 + (lane & 15);
    int h = k >> 7, kk = k & 127;
    Bp[t] = (_Float16)(0.125f * W2[kk*512 + h*64 + c]);
  } else if (b < SCAN_NB + 320){
    int t = (b - SCAN_NB - 256)*256 + t_;
    int j = t & 7, lane = (t >> 3) & 63, nt = (t >> 9) & 7, kt = t >> 12;
    int k = kt*32 + (lane >> 4)*8 + j;
    int c = nt*16 + (lane & 15);
    Bp1[t] = (_Float16)W1[k*128 + c];
  } else {
    int t = (b - SCAN_NB - 320)*256 + t_;
    int k = t >> 3, h = t & 7;
    float s = 0.f, d = 0.f;
    for (int dd = 0; dd < 64; dd++){
      float w = W2[k*512 + h*64 + dd];
      s += w * as2[h*64 + dd];
      d += w * ad2[h*64 + dd];
    }
    ws2[h*128 + k] = s;
    wd2[h*128 + k] = d;
  }
}

// ======== launch 2: degree histogram FUSED with layer-1 GEMM (independent) ========
// blocks [0,NB_DEG): degree atomics; [NB_DEG, NB_DEG+NB_GEMM1): h1 = x@W1 + alpha1.
__global__ void __launch_bounds__(256) k_deg_gemm1(
    const int* __restrict__ ei, int* __restrict__ deg, const int* __restrict__ flag,
    const float* __restrict__ x, const _Float16* __restrict__ Bp1,
    _Float16* __restrict__ h1,
    const float* __restrict__ as1, const float* __restrict__ ad1,
    float* __restrict__ als1, float* __restrict__ ald1){
  if (blockIdx.x < NB_DEG){
    int e = blockIdx.x*blockDim.x + threadIdx.x;
    if (e >= ET) return;
    int is64 = *flag;
    int d = edge_dst(ei, e, is64);
    atomicAdd(&deg[d], 1);
    return;
  }
  int bid = blockIdx.x - NB_DEG;
  int tid = threadIdx.x;
  int lane = tid & 63, wv = tid >> 6;
  int n0 = bid*64 + wv*16;
  int rowA = n0 + (lane & 15);
  int koff = (lane >> 4)*8;
  const float* xr = x + (size_t)rowA*128 + koff;
  f32x4 acc[8];
  #pragma unroll
  for (int i = 0; i < 8; i++) acc[i] = (f32x4){0.f,0.f,0.f,0.f};
  bool inb = (rowA < N_NODES);
  #pragma unroll
  for (int kt = 0; kt < 4; kt++){
    half8 af;
    if (inb){
      float4 a0 = *(const float4*)(xr + kt*32);
      float4 a1 = *(const float4*)(xr + kt*32 + 4);
      af = (half8){(_Float16)a0.x,(_Float16)a0.y,(_Float16)a0.z,(_Float16)a0.w,
                   (_Float16)a1.x,(_Float16)a1.y,(_Float16)a1.z,(_Float16)a1.w};
    } else {
      af = (half8){0,0,0,0,0,0,0,0};
    }
    #pragma unroll
    for (int nt = 0; nt < 8; nt++){
      half8 bf = *(const half8*)(Bp1 + (((kt*8 + nt)*64 + lane) << 3));
      acc[nt] = __builtin_amdgcn_mfma_f32_16x16x32_f16(af, bf, acc[nt], 0, 0, 0);
    }
  }
  int m = lane & 15, q = lane >> 4;
  int r0 = n0 + q*4;               // C/D: col=lane&15, row=(lane>>4)*4+reg  [m89]
  #pragma unroll
  for (int nt = 0; nt < 8; nt++){
    int c = nt*16 + m;
    #pragma unroll
    for (int r = 0; r < 4; r++){
      int n = r0 + r;
      if (n < N_NODES) h1[(size_t)n*128 + c] = (_Float16)acc[nt][r];
    }
  }
  // fused alpha1: lane's acc[nt][r] is channel (nt*16+m) == head nt, pos m of row r0+r
  float as1v[8], ad1v[8];
  #pragma unroll
  for (int nt = 0; nt < 8; nt++){
    as1v[nt] = as1[nt*16 + m];
    ad1v[nt] = ad1[nt*16 + m];
  }
  #pragma unroll
  for (int r = 0; r < 4; r++){
    float vs[8], vd[8];
    #pragma unroll
    for (int nt = 0; nt < 8; nt++){
      vs[nt] = acc[nt][r]*as1v[nt];
      vd[nt] = acc[nt][r]*ad1v[nt];
      #pragma unroll
      for (int off = 1; off < 16; off <<= 1){
        vs[nt] += __shfl_xor(vs[nt], off, 64);
        vd[nt] += __shfl_xor(vd[nt], off, 64);
      }
    }
    int n = r0 + r;
    if (m == r && n < N_NODES){
      float4 v0; v0.x = vs[0]; v0.y = vs[1]; v0.z = vs[2]; v0.w = vs[3];
      float4 v1; v1.x = vs[4]; v1.y = vs[5]; v1.z = vs[6]; v1.w = vs[7];
      float4 w0; w0.x = vd[0]; w0.y = vd[1]; w0.z = vd[2]; w0.w = vd[3];
      float4 w1; w1.x = vd[4]; w1.y = vd[5]; w1.z = vd[6]; w1.w = vd[7];
      *(float4*)&als1[n*8]     = v0;
      *(float4*)&als1[n*8 + 4] = v1;
      *(float4*)&ald1[n*8]     = w0;
      *(float4*)&ald1[n*8 + 4] = w1;
    }
  }
}

// ---- 3-stage scan ----
__global__ void k_scan_part(const int* __restrict__ deg, int* __restrict__ loc,
                            int* __restrict__ part){
  __shared__ int lds[256];
  int t = threadIdx.x, i = blockIdx.x*256 + t;
  int v = (i < N_NODES) ? deg[i] : 0;
  lds[t] = v;
  __syncthreads();
  for (int off = 1; off < 256; off <<= 1){
    int x = (t >= off) ? lds[t - off] : 0;
    __syncthreads();
    lds[t] += x;
    __syncthreads();
  }
  if (i < N_NODES) loc[i] = lds[t] - v;          // local exclusive
  if (t == 255) part[blockIdx.x] = lds[255];
}

__global__ void k_scan_carry(int* __restrict__ part, int* __restrict__ carry){
  __shared__ int lds[256];
  int t = threadIdx.x;
  int v = (t < SCAN_NB) ? part[t] : 0;
  lds[t] = v;
  __syncthreads();
  for (int off = 1; off < 256; off <<= 1){
    int x = (t >= off) ? lds[t - off] : 0;
    __syncthreads();
    lds[t] += x;
    __syncthreads();
  }
  if (t < SCAN_NB) carry[t] = lds[t] - v;        // exclusive over blocks
}

__global__ void k_scan_add(const int* __restrict__ loc, const int* __restrict__ carry,
                           int* __restrict__ row_ptr){
  int i = blockIdx.x*blockDim.x + threadIdx.x;
  if (i < N_NODES) row_ptr[i] = loc[i] + carry[i >> 8];
  if (i == 0) row_ptr[N_NODES] = ET;
}

__global__ void k_fill(const int* __restrict__ ei, const int* __restrict__ row_ptr,
                       int* __restrict__ cnt, int* __restrict__ col,
                       const int* __restrict__ flag){
  int e = blockIdx.x*blockDim.x + threadIdx.x;
  if (e >= ET) return;
  int is64 = *flag;
  int s = edge_src(ei, e, is64);
  int d = edge_dst(ei, e, is64);
  int pos = atomicAdd(&cnt[d], 1);
  col[row_ptr[d] + pos] = s;
}

// ===== layer 1: two-phase softmax+agg; WIDE phase-2 gather =====
// Phase 2 lane map (eg=lane>>4, cb=lane&15): lane handles edge j+eg, channels
// [cb*8,cb*8+8) (head hq=cb>>1) -> ONE half8 (dwordx4) load per 4 edges per lane
// (4x fewer VMEM instrs than the half2-per-lane layout); fp32 acc; cross-eg
// shfl reduce at the end. No cross-wave barrier (per-wave LDS + fence only).
__global__ void k_attn_agg1(const _Float16* __restrict__ h1,
    const float* __restrict__ als, const float* __restrict__ ald,
    const int* __restrict__ row_ptr, const int* __restrict__ col,
    const float* __restrict__ bias, _Float16* __restrict__ hr,
    const float* __restrict__ ws2, const float* __restrict__ wd2,
    float* __restrict__ als2, float* __restrict__ ald2){
  __shared__ _Float16 ew_s[4][CAP*8];
  __shared__ int col_s[4][CAP];
  __shared__ _Float16 ot_s[4][136];
  int tid = threadIdx.x;
  int wv = tid >> 6, lane = tid & 63;
  int n = blockIdx.x*4 + wv;              // grid exact: 12500*4 = 50000
  int beg = row_ptr[n], end = row_ptr[n+1];
  int deg = end - beg;
  int items = deg*8;
  int h = lane & 7;
  float ad = ald[n*8 + h];
  _Float16* es = ew_s[wv];
  int* cs = col_s[wv];
  float l = 0.f;
  int itc = items < CAP*8 ? items : CAP*8;
  int it = lane;
  for (; it < itc; it += 64){             // cached range: store es + col
    int e = it >> 3;
    int s = col[beg + e];
    float a = als[s*8 + h] + ad;
    a = (a > 0.f) ? a : 0.2f*a;
    float ex = __expf(a);
    es[it] = (_Float16)ex;
    if ((it & 7) == 0) cs[e] = s;
    l += ex;
  }
  for (; it < items; it += 64){           // rare overflow range
    int s = col[beg + (it >> 3)];
    float a = als[s*8 + h] + ad;
    a = (a > 0.f) ? a : 0.2f*a;
    l += __expf(a);
  }
  l += __shfl_xor(l, 8, 64);
  l += __shfl_xor(l, 16, 64);
  l += __shfl_xor(l, 32, 64);
  float inv = 1.f / (l + 1e-16f);
  wave_lds_fence();                       // own-wave LDS only: no __syncthreads
  // ---- phase 2: wide gather ----
  int eg = lane >> 4, cb = lane & 15;
  int hq = cb >> 1;                       // head owning channels cb*8..cb*8+7
  float invh = __shfl(inv, hq, 64);
  float adh  = __shfl(ad, hq, 64);        // ald[n*8+hq] (for overflow path)
  float acc[8];
  #pragma unroll
  for (int k = 0; k < 8; k++) acc[k] = 0.f;
  int degc = deg < CAP ? deg : CAP;
  int j = 0;
  for (; j + 3 < degc; j += 4){
    int e = j + eg;
    int s = cs[e];
    float w = (float)es[e*8 + hq] * invh;
    half8 v = *(const half8*)(h1 + (size_t)s*128 + cb*8);
    #pragma unroll
    for (int k = 0; k < 8; k++) acc[k] += w*(float)v[k];
  }
  if (j < degc){                          // tail (predicated, <=3 edges)
    int e = j + eg;
    if (e < degc){
      int s = cs[e];
      float w = (float)es[e*8 + hq] * invh;
      half8 v = *(const half8*)(h1 + (size_t)s*128 + cb*8);
      #pragma unroll
      for (int k = 0; k < 8; k++) acc[k] += w*(float)v[k];
    }
  }
  for (int jj = degc; jj < deg; jj += 4){ // rare: deg > CAP, recompute weights
    int e = jj + eg;
    if (e < deg){
      int s = col[beg + e];
      float a = als[s*8 + hq] + adh;
      a = (a > 0.f) ? a : 0.2f*a;
      float w = __expf(a)*invh;
      half8 v = *(const half8*)(h1 + (size_t)s*128 + cb*8);
      #pragma unroll
      for (int k = 0; k < 8; k++) acc[k] += w*(float)v[k];
    }
  }
  // cross-eg reduce (4 edge groups)
  #pragma unroll
  for (int k = 0; k < 8; k++){
    acc[k] += __shfl_xor(acc[k], 16, 64);
    acc[k] += __shfl_xor(acc[k], 32, 64);
  }
  // bias + ReLU; lanes eg==0 write the full row (16 lanes x 16B, coalesced)
  float4 b0 = *(const float4*)(bias + cb*8);
  float4 b1 = *(const float4*)(bias + cb*8 + 4);
  float bb[8] = {b0.x,b0.y,b0.z,b0.w,b1.x,b1.y,b1.z,b1.w};
  half8 oh;
  #pragma unroll
  for (int k = 0; k < 8; k++) oh[k] = (_Float16)fmaxf(acc[k] + bb[k], 0.f);
  if (eg == 0){
    *(half8*)(hr + (size_t)n*128 + cb*8) = oh;
    ((half8*)&ot_s[wv][0])[cb] = oh;      // same-wave LDS transpose staging
  }
  wave_lds_fence();
  // fused alpha2: lane -> (head hh=lane>>3, segment seg=lane&7)
  int hh = lane >> 3, seg = lane & 7;
  const half2v* otp = (const half2v*)&ot_s[wv][0];
  const float* wsr = ws2 + hh*128 + seg*16;
  const float* wdr = wd2 + hh*128 + seg*16;
  float vs = 0.f, vd = 0.f;
  #pragma unroll
  for (int i = 0; i < 8; i++){
    half2v v = otp[seg*8 + i];
    float vx = (float)v.x, vy = (float)v.y;
    vs += vx*wsr[2*i] + vy*wsr[2*i + 1];
    vd += vx*wdr[2*i] + vy*wdr[2*i + 1];
  }
  vs += __shfl_xor(vs, 1, 64); vd += __shfl_xor(vd, 1, 64);
  vs += __shfl_xor(vs, 2, 64); vd += __shfl_xor(vd, 2, 64);
  vs += __shfl_xor(vs, 4, 64); vd += __shfl_xor(vd, 4, 64);
  if (seg == 0){
    als2[n*8 + hh] = vs;
    ald2[n*8 + hh] = vd;
  }
}

// ===== layer 2 FUSED: softmax+agg (16 waves = 16 nodes) + output MFMA GEMM =====
// Phase 2 now uses the WIDE (eg,cb) gather: lane owns edge j+eg, channels
// [cb*8,cb*8+8), accumulating ALL 8 heads (acc[4][8] half2v, 32 VGPRs, static
// indices only). ONE half8 load + ONE ds_read_b128 per lane per 4 edges, zero
// lane redundancy (4x fewer VMEM instrs). es table normalized in place after
// phase 1, so phase-2 weights need no inv multiply. Cross-eg shfl reduce +
// cndmask head-pair select at the end. launch_bounds(1024,8) pins VGPR<=64.
__global__ void __launch_bounds__(1024, 8) k_attn_agg2(const _Float16* __restrict__ hr,
    const float* __restrict__ als, const float* __restrict__ ald,
    const int* __restrict__ row_ptr, const int* __restrict__ col,
    const _Float16* __restrict__ Bp, const float* __restrict__ b2,
    float* __restrict__ outp){
  __shared__ _Float16 ew_s[16][CAP*8];
  __shared__ int col_s[16][CAP];
  __shared__ _Float16 at[16*LRS];
  int tid = threadIdx.x;
  int wv = tid >> 6, lane = tid & 63;
  int n = blockIdx.x*16 + wv;             // grid exact: 3125*16 = 50000
  int beg = row_ptr[n], end = row_ptr[n+1];
  int deg = end - beg;
  int items = deg*8;
  int h = lane & 7;
  float ad = ald[n*8 + h];
  _Float16* es = ew_s[wv];
  int* cs = col_s[wv];
  float l = 0.f;
  int itc = items < CAP*8 ? items : CAP*8;
  int it = lane;
  for (; it < itc; it += 64){
    int e = it >> 3;
    int s = col[beg + e];
    float a = als[s*8 + h] + ad;
    a = (a > 0.f) ? a : 0.2f*a;
    float ex = __expf(a);
    es[it] = (_Float16)ex;
    if ((it & 7) == 0) cs[e] = s;
    l += ex;
  }
  for (; it < items; it += 64){
    int s = col[beg + (it >> 3)];
    float a = als[s*8 + h] + ad;
    a = (a > 0.f) ? a : 0.2f*a;
    l += __expf(a);
  }
  l += __shfl_xor(l, 8, 64);
  l += __shfl_xor(l, 16, 64);
  l += __shfl_xor(l, 32, 64);
  float inv = 1.f / (l + 1e-16f);   // for head lane&7 (lanes with same lane&7 agree)
  wave_lds_fence();
  // normalize es in place: each lane rescales exactly the entries it wrote
  for (int it2 = lane; it2 < itc; it2 += 64){
    es[it2] = (_Float16)((float)es[it2] * inv);
  }
  wave_lds_fence();                 // own-wave LDS only: no cross-wave barrier here
  int eg = lane >> 4, cb = lane & 15;
  half2v acc[4][8];                 // [ch-pair p][head hh] - static indices only
  #pragma unroll
  for (int p = 0; p < 4; p++)
    #pragma unroll
    for (int hh = 0; hh < 8; hh++)
      acc[p][hh] = (half2v){(_Float16)0.f, (_Float16)0.f};
  int degc = deg < CAP ? deg : CAP;
  for (int j = 0; j < degc; j += 4){
    int e = j + eg;
    bool act = (e < degc);
    int ec = act ? e : 0;
    int s = cs[ec];
    half8 we = *(const half8*)(es + ec*8);      // normalized weights, 8 heads
    half8 v  = *(const half8*)(hr + (size_t)s*128 + cb*8);
    if (!act) we = (half8){0,0,0,0,0,0,0,0};
    #pragma unroll
    for (int p = 0; p < 4; p++){
      half2v t = (half2v){v[2*p], v[2*p+1]};
      acc[p][0] += (half2v){we[0], we[0]} * t;
      acc[p][1] += (half2v){we[1], we[1]} * t;
      acc[p][2] += (half2v){we[2], we[2]} * t;
      acc[p][3] += (half2v){we[3], we[3]} * t;
      acc[p][4] += (half2v){we[4], we[4]} * t;
      acc[p][5] += (half2v){we[5], we[5]} * t;
      acc[p][6] += (half2v){we[6], we[6]} * t;
      acc[p][7] += (half2v){we[7], we[7]} * t;
    }
  }
  if (deg > CAP){                   // rare: deg > CAP, recompute weights on the fly
    float invs[8], advs[8];
    #pragma unroll
    for (int hh = 0; hh < 8; hh++){
      invs[hh] = __shfl(inv, hh, 64);
      advs[hh] = __shfl(ad, hh, 64);
    }
    for (int jj = degc; jj < deg; jj += 4){
      int e = jj + eg;
      if (e < deg){
        int s = col[beg + e];
        float4 a0 = *(const float4*)(als + (size_t)s*8);
        float4 a1 = *(const float4*)(als + (size_t)s*8 + 4);
        float av[8] = {a0.x,a0.y,a0.z,a0.w,a1.x,a1.y,a1.z,a1.w};
        half8 we;
        #pragma unroll
        for (int hh = 0; hh < 8; hh++){
          float a = av[hh] + advs[hh];
          a = (a > 0.f) ? a : 0.2f*a;
          we[hh] = (_Float16)(__expf(a)*invs[hh]);
        }
        half8 v = *(const half8*)(hr + (size_t)s*128 + cb*8);
        #pragma unroll
        for (int p = 0; p < 4; p++){
          half2v t = (half2v){v[2*p], v[2*p+1]};
          acc[p][0] += (half2v){we[0], we[0]} * t;
          acc[p][1] += (half2v){we[1], we[1]} * t;
          acc[p][2] += (half2v){we[2], we[2]} * t;
          acc[p][3] += (half2v){we[3], we[3]} * t;
          acc[p][4] += (half2v){we[4], we[4]} * t;
          acc[p][5] += (half2v){we[5], we[5]} * t;
          acc[p][6] += (half2v){we[6], we[6]} * t;
          acc[p][7] += (half2v){we[7], we[7]} * t;
        }
      }
    }
  }
  // cross-eg reduce (4 edge groups); half2v is 32-bit -> shfl via bit_cast
  #pragma unroll
  for (int p = 0; p < 4; p++){
    #pragma unroll
    for (int hh = 0; hh < 8; hh++){
      int b0 = __builtin_bit_cast(int, acc[p][hh]);
      acc[p][hh] += __builtin_bit_cast(half2v, __shfl_xor(b0, 16, 64));
      int b1 = __builtin_bit_cast(int, acc[p][hh]);
      acc[p][hh] += __builtin_bit_cast(half2v, __shfl_xor(b1, 32, 64));
    }
  }
  // head-pair select (heads 2eg, 2eg+1) via cndmask chains - no runtime indexing
  half8 oa, ob;
  #pragma unroll
  for (int p = 0; p < 4; p++){
    half2v ra = (eg == 0) ? acc[p][0] : (eg == 1) ? acc[p][2]
              : (eg == 2) ? acc[p][4] : acc[p][6];
    half2v rb = (eg == 0) ? acc[p][1] : (eg == 1) ? acc[p][3]
              : (eg == 2) ? acc[p][5] : acc[p][7];
    oa[2*p] = ra.x; oa[2*p+1] = ra.y;
    ob[2*p] = rb.x; ob[2*p+1] = rb.y;
  }
  _Float16* ar = at + wv*LRS + (2*eg)*128 + cb*8;
  *(half8*)ar = oa;
  *(half8*)(ar + 128) = ob;
  __syncthreads();
  if (wv >= 4) return;
  // MFMA epilogue: wave wv = output col-tile nt; A from LDS, Bp L2-hot
  int m = lane & 15, q = lane >> 4;
  const _Float16* arow = at + m*LRS + q*8;
  f32x4 cacc = (f32x4){0.f,0.f,0.f,0.f};
  #pragma unroll 4
  for (int kt = 0; kt < 32; kt++){
    half8 af = *(const half8*)(arow + kt*32);
    half8 bf = *(const half8*)(Bp + (((kt*4 + wv)*64 + lane) << 3));
    cacc = __builtin_amdgcn_mfma_f32_16x16x32_f16(af, bf, cacc, 0, 0, 0);
  }
  int c = wv*16 + m;
  float bb = b2[c];
  #pragma unroll
  for (int r = 0; r < 4; r++){
    int nrow = blockIdx.x*16 + q*4 + r;   // C/D: col=lane&15, row=(lane>>4)*4+reg [m89]
    outp[(size_t)nrow*64 + c] = cacc[r] + bb;
  }
}

extern "C" void kernel_launch(void* const* d_in, const int* in_sizes, int n_in,
                              void* d_out, int out_size, void* d_ws, size_t ws_size,
                              hipStream_t stream){
  const float* x   = (const float*)d_in[0];
  const int*   ei  = (const int*)d_in[1];
  const float* W1  = (const float*)d_in[2];
  const float* as1 = (const float*)d_in[3];
  const float* ad1 = (const float*)d_in[4];
  const float* b1  = (const float*)d_in[5];
  const float* W2  = (const float*)d_in[6];
  const float* as2 = (const float*)d_in[7];
  const float* ad2 = (const float*)d_in[8];
  const float* b2  = (const float*)d_in[9];
  float* outp = (float*)d_out;

  char* p = (char*)d_ws;
  auto alloc = [&](size_t bytes) -> void* {
    void* r = (void*)p;
    p += (bytes + 255) & ~(size_t)255;
    return r;
  };
  _Float16* h1  = (_Float16*)alloc((size_t)NPAD*128*2);          // [N,128] fp16
  _Float16* hr  = (_Float16*)alloc((size_t)N_NODES*128*2);       // [N,128] fp16
  float* als1 = (float*)alloc((size_t)N_NODES*8*4);
  float* ald1 = (float*)alloc((size_t)N_NODES*8*4);
  float* als2 = (float*)alloc((size_t)N_NODES*8*4);
  float* ald2 = (float*)alloc((size_t)N_NODES*8*4);
  int* row_ptr = (int*)alloc((size_t)(N_NODES+1)*4);
  int* deg  = (int*)alloc((size_t)N_NODES*4);
  int* cnt  = (int*)alloc((size_t)N_NODES*4);
  int* col  = (int*)alloc((size_t)ET*4);
  int* loc  = (int*)alloc((size_t)N_NODES*4);
  int* part = (int*)alloc(256*4);
  int* carry= (int*)alloc(256*4);
  int* flag = (int*)alloc(256);
  float* ws2 = (float*)alloc(1024*4);
  float* wd2 = (float*)alloc(1024*4);
  _Float16* Bp1 = (_Float16*)alloc((size_t)16384*2);
  _Float16* Bp  = (_Float16*)alloc((size_t)65536*2);

  dim3 b256(256);
  // launch 1: init + weight prep (independent block ranges)
  k_init_wprep<<<SCAN_NB + 324, b256, 0, stream>>>(ei, deg, cnt, flag,
                                                   W1, W2, as2, ad2,
                                                   Bp1, Bp, ws2, wd2);
  // launch 2: degree atomics || layer-1 GEMM (independent, overlapped)
  k_deg_gemm1<<<NB_DEG + NB_GEMM1, b256, 0, stream>>>(ei, deg, flag,
                                                      x, Bp1, h1, as1, ad1,
                                                      als1, ald1);
  // CSR scan + fill
  k_scan_part<<<SCAN_NB, b256, 0, stream>>>(deg, loc, part);
  k_scan_carry<<<1, b256, 0, stream>>>(part, carry);
  k_scan_add<<<SCAN_NB, b256, 0, stream>>>(loc, carry, row_ptr);
  k_fill<<<(ET+255)/256, b256, 0, stream>>>(ei, row_ptr, cnt, col, flag);
  // layer 1 softmax+agg (alpha2 fused)
  k_attn_agg1<<<N_NODES/4, b256, 0, stream>>>(h1, als1, ald1, row_ptr, col,
                                              b1, hr, ws2, wd2, als2, ald2);
  // layer 2: fused softmax+agg+output-GEMM
  k_attn_agg2<<<N_NODES/16, dim3(1024), 0, stream>>>(hr, als2, ald2, row_ptr, col,
                                                     Bp, b2, outp);
}

// Round 9
// 342.733 us; speedup vs baseline: 1.0227x; 1.0227x over previous
//
#include <hip/hip_runtime.h>

#define N_NODES 50000
#define N_EDGES 800000
#define ET (N_EDGES + N_NODES)   // 850000 incl. self loops
#define HEADS 8
#define NPAD 50048               // 782 blocks * 64 nodes
#define SCAN_NB 196              // ceil(50000/256)
#define CAP 96                   // LDS-cached edges per node (deg>CAP -> recompute)
#define LRS 1032                 // LDS A-tile row stride (halves, 16B-aligned)
#define NB_DEG 3321              // ceil(850000/256)
#define NB_GEMM1 782             // NPAD/64

typedef __attribute__((ext_vector_type(8))) _Float16 half8;
typedef __attribute__((ext_vector_type(2))) _Float16 half2v;
typedef __attribute__((ext_vector_type(4))) float f32x4;

// wave-local LDS fence: drains this wave's outstanding DS ops (same-wave
// cross-lane LDS write->read; consumers are ds_reads, ordered by "memory").
__device__ __forceinline__ void wave_lds_fence(){
  asm volatile("s_waitcnt lgkmcnt(0)" ::: "memory");
}

__device__ __forceinline__ int edge_src(const int* ei, int e, int is64){
  if (e >= N_EDGES) return e - N_EDGES;          // self loop
  return is64 ? ei[2*e] : ei[e];
}
__device__ __forceinline__ int edge_dst(const int* ei, int e, int is64){
  if (e >= N_EDGES) return e - N_EDGES;          // self loop
  return is64 ? ei[2*(N_EDGES + e)] : ei[N_EDGES + e];
}

// ======== launch 1: init (zero deg/cnt + layout probe) FUSED with wprep ========
// blocks [0,196): init; [196,452): W2 pack; [452,516): W1 pack; [516,520): wtilde
__global__ void k_init_wprep(const int* __restrict__ ei, int* __restrict__ deg,
                             int* __restrict__ cnt, int* __restrict__ flag,
                             const float* __restrict__ W1, const float* __restrict__ W2,
                             const float* __restrict__ as2, const float* __restrict__ ad2,
                             _Float16* __restrict__ Bp1, _Float16* __restrict__ Bp,
                             float* __restrict__ ws2, float* __restrict__ wd2){
  int b = blockIdx.x;
  int t_ = threadIdx.x;
  if (b < SCAN_NB){
    int i = b*256 + t_;
    if (i < N_NODES){ deg[i] = 0; cnt[i] = 0; }
    if (i == 0){
      int zeros = 0;
      for (int k = 0; k < 64; k++){
        if (ei[2*k + 1] == 0) zeros++;
      }
      *flag = (zeros >= 60) ? 1 : 0;   // 1 => int64 little-endian layout
    }
  } else if (b < SCAN_NB + 256){
    int t = (b - SCAN_NB)*256 + t_;
    int j = t & 7, lane = (t >> 3) & 63, nt = (t >> 9) & 3, kt = t >> 11;
    int k = kt*32 + (lane >> 4)*8 + j;
    int c = nt*16 + (lane & 15);
    int h = k >> 7, kk = k & 127;
    Bp[t] = (_Float16)(0.125f * W2[kk*512 + h*64 + c]);
  } else if (b < SCAN_NB + 320){
    int t = (b - SCAN_NB - 256)*256 + t_;
    int j = t & 7, lane = (t >> 3) & 63, nt = (t >> 9) & 7, kt = t >> 12;
    int k = kt*32 + (lane >> 4)*8 + j;
    int c = nt*16 + (lane & 15);
    Bp1[t] = (_Float16)W1[k*128 + c];
  } else {
    int t = (b - SCAN_NB - 320)*256 + t_;
    int k = t >> 3, h = t & 7;
    float s = 0.f, d = 0.f;
    for (int dd = 0; dd < 64; dd++){
      float w = W2[k*512 + h*64 + dd];
      s += w * as2[h*64 + dd];
      d += w * ad2[h*64 + dd];
    }
    ws2[h*128 + k] = s;
    wd2[h*128 + k] = d;
  }
}

// ======== launch 2: degree histogram FUSED with layer-1 GEMM (independent) ========
// blocks [0,NB_DEG): degree atomics; [NB_DEG, NB_DEG+NB_GEMM1): h1 = x@W1 + alpha1.
__global__ void __launch_bounds__(256) k_deg_gemm1(
    const int* __restrict__ ei, int* __restrict__ deg, const int* __restrict__ flag,
    const float* __restrict__ x, const _Float16* __restrict__ Bp1,
    _Float16* __restrict__ h1,
    const float* __restrict__ as1, const float* __restrict__ ad1,
    float* __restrict__ als1, float* __restrict__ ald1){
  if (blockIdx.x < NB_DEG){
    int e = blockIdx.x*blockDim.x + threadIdx.x;
    if (e >= ET) return;
    int is64 = *flag;
    int d = edge_dst(ei, e, is64);
    atomicAdd(&deg[d], 1);
    return;
  }
  int bid = blockIdx.x - NB_DEG;
  int tid = threadIdx.x;
  int lane = tid & 63, wv = tid >> 6;
  int n0 = bid*64 + wv*16;
  int rowA = n0 + (lane & 15);
  int koff = (lane >> 4)*8;
  const float* xr = x + (size_t)rowA*128 + koff;
  f32x4 acc[8];
  #pragma unroll
  for (int i = 0; i < 8; i++) acc[i] = (f32x4){0.f,0.f,0.f,0.f};
  bool inb = (rowA < N_NODES);
  #pragma unroll
  for (int kt = 0; kt < 4; kt++){
    half8 af;
    if (inb){
      float4 a0 = *(const float4*)(xr + kt*32);
      float4 a1 = *(const float4*)(xr + kt*32 + 4);
      af = (half8){(_Float16)a0.x,(_Float16)a0.y,(_Float16)a0.z,(_Float16)a0.w,
                   (_Float16)a1.x,(_Float16)a1.y,(_Float16)a1.z,(_Float16)a1.w};
    } else {
      af = (half8){0,0,0,0,0,0,0,0};
    }
    #pragma unroll
    for (int nt = 0; nt < 8; nt++){
      half8 bf = *(const half8*)(Bp1 + (((kt*8 + nt)*64 + lane) << 3));
      acc[nt] = __builtin_amdgcn_mfma_f32_16x16x32_f16(af, bf, acc[nt], 0, 0, 0);
    }
  }
  int m = lane & 15, q = lane >> 4;
  int r0 = n0 + q*4;               // C/D: col=lane&15, row=(lane>>4)*4+reg  [m89]
  #pragma unroll
  for (int nt = 0; nt < 8; nt++){
    int c = nt*16 + m;
    #pragma unroll
    for (int r = 0; r < 4; r++){
      int n = r0 + r;
      if (n < N_NODES) h1[(size_t)n*128 + c] = (_Float16)acc[nt][r];
    }
  }
  // fused alpha1: lane's acc[nt][r] is channel (nt*16+m) == head nt, pos m of row r0+r
  float as1v[8], ad1v[8];
  #pragma unroll
  for (int nt = 0; nt < 8; nt++){
    as1v[nt] = as1[nt*16 + m];
    ad1v[nt] = ad1[nt*16 + m];
  }
  #pragma unroll
  for (int r = 0; r < 4; r++){
    float vs[8], vd[8];
    #pragma unroll
    for (int nt = 0; nt < 8; nt++){
      vs[nt] = acc[nt][r]*as1v[nt];
      vd[nt] = acc[nt][r]*ad1v[nt];
      #pragma unroll
      for (int off = 1; off < 16; off <<= 1){
        vs[nt] += __shfl_xor(vs[nt], off, 64);
        vd[nt] += __shfl_xor(vd[nt], off, 64);
      }
    }
    int n = r0 + r;
    if (m == r && n < N_NODES){
      float4 v0; v0.x = vs[0]; v0.y = vs[1]; v0.z = vs[2]; v0.w = vs[3];
      float4 v1; v1.x = vs[4]; v1.y = vs[5]; v1.z = vs[6]; v1.w = vs[7];
      float4 w0; w0.x = vd[0]; w0.y = vd[1]; w0.z = vd[2]; w0.w = vd[3];
      float4 w1; w1.x = vd[4]; w1.y = vd[5]; w1.z = vd[6]; w1.w = vd[7];
      *(float4*)&als1[n*8]     = v0;
      *(float4*)&als1[n*8 + 4] = v1;
      *(float4*)&ald1[n*8]     = w0;
      *(float4*)&ald1[n*8 + 4] = w1;
    }
  }
}

// ---- single-pass brute-force scan: block b sums deg[0..b*256) directly ----
// (replaces 3-launch scan chain; total extra reads 19.6MB ~ 3us at HBM BW)
__global__ void k_scan(const int* __restrict__ deg, int* __restrict__ row_ptr){
  __shared__ int lds[256];
  int t = threadIdx.x, b = blockIdx.x;
  int lim = b*256;
  int pre = 0;
  for (int i = t; i < lim; i += 256) pre += deg[i];   // coalesced grid-stride
  lds[t] = pre;
  __syncthreads();
  #pragma unroll
  for (int off = 128; off > 0; off >>= 1){
    if (t < off) lds[t] += lds[t + off];
    __syncthreads();
  }
  int base = lds[0];
  __syncthreads();
  int i = lim + t;
  int v = (i < N_NODES) ? deg[i] : 0;
  lds[t] = v;
  __syncthreads();
  for (int off = 1; off < 256; off <<= 1){
    int x = (t >= off) ? lds[t - off] : 0;
    __syncthreads();
    lds[t] += x;
    __syncthreads();
  }
  if (i < N_NODES) row_ptr[i] = base + lds[t] - v;    // exclusive prefix
  if (i == 0) row_ptr[N_NODES] = ET;
}

__global__ void k_fill(const int* __restrict__ ei, const int* __restrict__ row_ptr,
                       int* __restrict__ cnt, int* __restrict__ col,
                       const int* __restrict__ flag){
  int e = blockIdx.x*blockDim.x + threadIdx.x;
  if (e >= ET) return;
  int is64 = *flag;
  int s = edge_src(ei, e, is64);
  int d = edge_dst(ei, e, is64);
  int pos = atomicAdd(&cnt[d], 1);
  col[row_ptr[d] + pos] = s;
}

// ===== layer 1: two-phase softmax+agg; WIDE phase-2 gather =====
// Phase 2 lane map (eg=lane>>4, cb=lane&15): lane handles edge j+eg, channels
// [cb*8,cb*8+8) (head hq=cb>>1) -> ONE half8 (dwordx4) load per 4 edges per lane
// (4x fewer VMEM instrs than the half2-per-lane layout); fp32 acc; cross-eg
// shfl reduce at the end. No cross-wave barrier (per-wave LDS + fence only).
__global__ void k_attn_agg1(const _Float16* __restrict__ h1,
    const float* __restrict__ als, const float* __restrict__ ald,
    const int* __restrict__ row_ptr, const int* __restrict__ col,
    const float* __restrict__ bias, _Float16* __restrict__ hr,
    const float* __restrict__ ws2, const float* __restrict__ wd2,
    float* __restrict__ als2, float* __restrict__ ald2){
  __shared__ _Float16 ew_s[4][CAP*8];
  __shared__ int col_s[4][CAP];
  __shared__ _Float16 ot_s[4][136];
  int tid = threadIdx.x;
  int wv = tid >> 6, lane = tid & 63;
  int n = blockIdx.x*4 + wv;              // grid exact: 12500*4 = 50000
  int beg = row_ptr[n], end = row_ptr[n+1];
  int deg = end - beg;
  int items = deg*8;
  int h = lane & 7;
  float ad = ald[n*8 + h];
  _Float16* es = ew_s[wv];
  int* cs = col_s[wv];
  float l = 0.f;
  int itc = items < CAP*8 ? items : CAP*8;
  int it = lane;
  for (; it < itc; it += 64){             // cached range: store es + col
    int e = it >> 3;
    int s = col[beg + e];
    float a = als[s*8 + h] + ad;
    a = (a > 0.f) ? a : 0.2f*a;
    float ex = __expf(a);
    es[it] = (_Float16)ex;
    if ((it & 7) == 0) cs[e] = s;
    l += ex;
  }
  for (; it < items; it += 64){           // rare overflow range
    int s = col[beg + (it >> 3)];
    float a = als[s*8 + h] + ad;
    a = (a > 0.f) ? a : 0.2f*a;
    l += __expf(a);
  }
  l += __shfl_xor(l, 8, 64);
  l += __shfl_xor(l, 16, 64);
  l += __shfl_xor(l, 32, 64);
  float inv = 1.f / (l + 1e-16f);
  wave_lds_fence();                       // own-wave LDS only: no __syncthreads
  // ---- phase 2: wide gather ----
  int eg = lane >> 4, cb = lane & 15;
  int hq = cb >> 1;                       // head owning channels cb*8..cb*8+7
  float invh = __shfl(inv, hq, 64);
  float adh  = __shfl(ad, hq, 64);        // ald[n*8+hq] (for overflow path)
  float acc[8];
  #pragma unroll
  for (int k = 0; k < 8; k++) acc[k] = 0.f;
  int degc = deg < CAP ? deg : CAP;
  int j = 0;
  for (; j + 3 < degc; j += 4){
    int e = j + eg;
    int s = cs[e];
    float w = (float)es[e*8 + hq] * invh;
    half8 v = *(const half8*)(h1 + (size_t)s*128 + cb*8);
    #pragma unroll
    for (int k = 0; k < 8; k++) acc[k] += w*(float)v[k];
  }
  if (j < degc){                          // tail (predicated, <=3 edges)
    int e = j + eg;
    if (e < degc){
      int s = cs[e];
      float w = (float)es[e*8 + hq] * invh;
      half8 v = *(const half8*)(h1 + (size_t)s*128 + cb*8);
      #pragma unroll
      for (int k = 0; k < 8; k++) acc[k] += w*(float)v[k];
    }
  }
  for (int jj = degc; jj < deg; jj += 4){ // rare: deg > CAP, recompute weights
    int e = jj + eg;
    if (e < deg){
      int s = col[beg + e];
      float a = als[s*8 + hq] + adh;
      a = (a > 0.f) ? a : 0.2f*a;
      float w = __expf(a)*invh;
      half8 v = *(const half8*)(h1 + (size_t)s*128 + cb*8);
      #pragma unroll
      for (int k = 0; k < 8; k++) acc[k] += w*(float)v[k];
    }
  }
  // cross-eg reduce (4 edge groups)
  #pragma unroll
  for (int k = 0; k < 8; k++){
    acc[k] += __shfl_xor(acc[k], 16, 64);
    acc[k] += __shfl_xor(acc[k], 32, 64);
  }
  // bias + ReLU; lanes eg==0 write the full row (16 lanes x 16B, coalesced)
  float4 b0 = *(const float4*)(bias + cb*8);
  float4 b1 = *(const float4*)(bias + cb*8 + 4);
  float bb[8] = {b0.x,b0.y,b0.z,b0.w,b1.x,b1.y,b1.z,b1.w};
  half8 oh;
  #pragma unroll
  for (int k = 0; k < 8; k++) oh[k] = (_Float16)fmaxf(acc[k] + bb[k], 0.f);
  if (eg == 0){
    *(half8*)(hr + (size_t)n*128 + cb*8) = oh;
    ((half8*)&ot_s[wv][0])[cb] = oh;      // same-wave LDS transpose staging
  }
  wave_lds_fence();
  // fused alpha2: lane -> (head hh=lane>>3, segment seg=lane&7)
  int hh = lane >> 3, seg = lane & 7;
  const half2v* otp = (const half2v*)&ot_s[wv][0];
  const float* wsr = ws2 + hh*128 + seg*16;
  const float* wdr = wd2 + hh*128 + seg*16;
  float vs = 0.f, vd = 0.f;
  #pragma unroll
  for (int i = 0; i < 8; i++){
    half2v v = otp[seg*8 + i];
    float vx = (float)v.x, vy = (float)v.y;
    vs += vx*wsr[2*i] + vy*wsr[2*i + 1];
    vd += vx*wdr[2*i] + vy*wdr[2*i + 1];
  }
  vs += __shfl_xor(vs, 1, 64); vd += __shfl_xor(vd, 1, 64);
  vs += __shfl_xor(vs, 2, 64); vd += __shfl_xor(vd, 2, 64);
  vs += __shfl_xor(vs, 4, 64); vd += __shfl_xor(vd, 4, 64);
  if (seg == 0){
    als2[n*8 + hh] = vs;
    ald2[n*8 + hh] = vd;
  }
}

// ===== layer 2 FUSED: softmax+agg (16 waves = 16 nodes) + output MFMA GEMM =====
// R7 form (measured best): two-phase LDS exp table, (hp,cb) gather, unroll-4,
// 28 VGPR; mid barrier = wave-local fence; one __syncthreads before MFMA.
__global__ void __launch_bounds__(1024) k_attn_agg2(const _Float16* __restrict__ hr,
    const float* __restrict__ als, const float* __restrict__ ald,
    const int* __restrict__ row_ptr, const int* __restrict__ col,
    const _Float16* __restrict__ Bp, const float* __restrict__ b2,
    float* __restrict__ outp){
  __shared__ _Float16 ew_s[16][CAP*8];
  __shared__ int col_s[16][CAP];
  __shared__ _Float16 at[16*LRS];
  int tid = threadIdx.x;
  int wv = tid >> 6, lane = tid & 63;
  int n = blockIdx.x*16 + wv;             // grid exact: 3125*16 = 50000
  int beg = row_ptr[n], end = row_ptr[n+1];
  int deg = end - beg;
  int items = deg*8;
  int h = lane & 7;
  float ad = ald[n*8 + h];
  _Float16* es = ew_s[wv];
  int* cs = col_s[wv];
  float l = 0.f;
  int itc = items < CAP*8 ? items : CAP*8;
  int it = lane;
  for (; it < itc; it += 64){
    int e = it >> 3;
    int s = col[beg + e];
    float a = als[s*8 + h] + ad;
    a = (a > 0.f) ? a : 0.2f*a;
    float ex = __expf(a);
    es[it] = (_Float16)ex;
    if ((it & 7) == 0) cs[e] = s;
    l += ex;
  }
  for (; it < items; it += 64){
    int s = col[beg + (it >> 3)];
    float a = als[s*8 + h] + ad;
    a = (a > 0.f) ? a : 0.2f*a;
    l += __expf(a);
  }
  l += __shfl_xor(l, 8, 64);
  l += __shfl_xor(l, 16, 64);
  l += __shfl_xor(l, 32, 64);
  float inv = 1.f / (l + 1e-16f);   // for head lane&7 (lanes with same lane&7 agree)
  wave_lds_fence();                 // own-wave LDS only: no cross-wave barrier here
  int hp = lane >> 4, cb = lane & 15;
  float invA = __shfl(inv, 2*hp, 64);       // inv for head 2hp   (held by lane 2hp)
  float invB = __shfl(inv, 2*hp + 1, 64);   // inv for head 2hp+1
  half2v inv2; inv2.x = (_Float16)invA; inv2.y = (_Float16)invB;
  half2v acc_a[4], acc_b[4];
  #pragma unroll
  for (int i = 0; i < 4; i++){
    acc_a[i] = (half2v){(_Float16)0.f, (_Float16)0.f};
    acc_b[i] = (half2v){(_Float16)0.f, (_Float16)0.f};
  }
  int degc = deg < CAP ? deg : CAP;
  const _Float16* esw = es + 2*hp;          // per-lane weight base (both heads, u32)
  int j = 0;
  for (; j + 3 < degc; j += 4){
    int s0 = cs[j], s1 = cs[j+1], s2 = cs[j+2], s3 = cs[j+3];
    half2v w0 = *(const half2v*)(esw + (j+0)*8) * inv2;
    half2v w1 = *(const half2v*)(esw + (j+1)*8) * inv2;
    half2v w2 = *(const half2v*)(esw + (j+2)*8) * inv2;
    half2v w3 = *(const half2v*)(esw + (j+3)*8) * inv2;
    half8 v0 = *(const half8*)(hr + (size_t)s0*128 + cb*8);
    half8 v1 = *(const half8*)(hr + (size_t)s1*128 + cb*8);
    half8 v2 = *(const half8*)(hr + (size_t)s2*128 + cb*8);
    half8 v3 = *(const half8*)(hr + (size_t)s3*128 + cb*8);
    #pragma unroll
    for (int k = 0; k < 4; k++){
      half2v t;
      t = (half2v){v0[2*k], v0[2*k+1]};
      acc_a[k] += (half2v){w0.x, w0.x} * t;
      acc_b[k] += (half2v){w0.y, w0.y} * t;
      t = (half2v){v1[2*k], v1[2*k+1]};
      acc_a[k] += (half2v){w1.x, w1.x} * t;
      acc_b[k] += (half2v){w1.y, w1.y} * t;
      t = (half2v){v2[2*k], v2[2*k+1]};
      acc_a[k] += (half2v){w2.x, w2.x} * t;
      acc_b[k] += (half2v){w2.y, w2.y} * t;
      t = (half2v){v3[2*k], v3[2*k+1]};
      acc_a[k] += (half2v){w3.x, w3.x} * t;
      acc_b[k] += (half2v){w3.y, w3.y} * t;
    }
  }
  for (; j < degc; j++){
    int s = cs[j];
    half2v w = *(const half2v*)(esw + j*8) * inv2;
    half8 v = *(const half8*)(hr + (size_t)s*128 + cb*8);
    #pragma unroll
    for (int k = 0; k < 4; k++){
      half2v t = (half2v){v[2*k], v[2*k+1]};
      acc_a[k] += (half2v){w.x, w.x} * t;
      acc_b[k] += (half2v){w.y, w.y} * t;
    }
  }
  if (deg > CAP){                             // rare: deg > CAP, recompute weights
    float2 adv = *(const float2*)(ald + (size_t)n*8 + 2*hp);
    for (; j < deg; j++){
      int s = col[beg + j];
      float2 alv = *(const float2*)(als + (size_t)s*8 + 2*hp);
      float a0 = alv.x + adv.x; a0 = (a0 > 0.f) ? a0 : 0.2f*a0;
      float a1 = alv.y + adv.y; a1 = (a1 > 0.f) ? a1 : 0.2f*a1;
      _Float16 w0 = (_Float16)(__expf(a0)*invA);
      _Float16 w1 = (_Float16)(__expf(a1)*invB);
      half8 v = *(const half8*)(hr + (size_t)s*128 + cb*8);
      #pragma unroll
      for (int k = 0; k < 4; k++){
        half2v t = (half2v){v[2*k], v[2*k+1]};
        acc_a[k] += (half2v){w0, w0} * t;
        acc_b[k] += (half2v){w1, w1} * t;
      }
    }
  }
  // write normalized rows into the LDS A-tile: head 2hp and 2hp+1, channels cb*8..
  _Float16* ar = at + wv*LRS + (2*hp)*128 + cb*8;
  half8 oa, ob;
  #pragma unroll
  for (int k = 0; k < 4; k++){
    oa[2*k] = acc_a[k].x; oa[2*k+1] = acc_a[k].y;
    ob[2*k] = acc_b[k].x; ob[2*k+1] = acc_b[k].y;
  }
  *(half8*)ar = oa;
  *(half8*)(ar + 128) = ob;
  __syncthreads();
  if (wv >= 4) return;
  // MFMA epilogue: wave wv = output col-tile nt; A from LDS, Bp L2-hot
  int m = lane & 15, q = lane >> 4;
  const _Float16* arow = at + m*LRS + q*8;
  f32x4 cacc = (f32x4){0.f,0.f,0.f,0.f};
  #pragma unroll 4
  for (int kt = 0; kt < 32; kt++){
    half8 af = *(const half8*)(arow + kt*32);
    half8 bf = *(const half8*)(Bp + (((kt*4 + wv)*64 + lane) << 3));
    cacc = __builtin_amdgcn_mfma_f32_16x16x32_f16(af, bf, cacc, 0, 0, 0);
  }
  int c = wv*16 + m;
  float bb = b2[c];
  #pragma unroll
  for (int r = 0; r < 4; r++){
    int nrow = blockIdx.x*16 + q*4 + r;   // C/D: col=lane&15, row=(lane>>4)*4+reg [m89]
    outp[(size_t)nrow*64 + c] = cacc[r] + bb;
  }
}

extern "C" void kernel_launch(void* const* d_in, const int* in_sizes, int n_in,
                              void* d_out, int out_size, void* d_ws, size_t ws_size,
                              hipStream_t stream){
  const float* x   = (const float*)d_in[0];
  const int*   ei  = (const int*)d_in[1];
  const float* W1  = (const float*)d_in[2];
  const float* as1 = (const float*)d_in[3];
  const float* ad1 = (const float*)d_in[4];
  const float* b1  = (const float*)d_in[5];
  const float* W2  = (const float*)d_in[6];
  const float* as2 = (const float*)d_in[7];
  const float* ad2 = (const float*)d_in[8];
  const float* b2  = (const float*)d_in[9];
  float* outp = (float*)d_out;

  char* p = (char*)d_ws;
  auto alloc = [&](size_t bytes) -> void* {
    void* r = (void*)p;
    p += (bytes + 255) & ~(size_t)255;
    return r;
  };
  _Float16* h1  = (_Float16*)alloc((size_t)NPAD*128*2);          // [N,128] fp16
  _Float16* hr  = (_Float16*)alloc((size_t)N_NODES*128*2);       // [N,128] fp16
  float* als1 = (float*)alloc((size_t)N_NODES*8*4);
  float* ald1 = (float*)alloc((size_t)N_NODES*8*4);
  float* als2 = (float*)alloc((size_t)N_NODES*8*4);
  float* ald2 = (float*)alloc((size_t)N_NODES*8*4);
  int* row_ptr = (int*)alloc((size_t)(N_NODES+1)*4);
  int* deg  = (int*)alloc((size_t)N_NODES*4);
  int* cnt  = (int*)alloc((size_t)N_NODES*4);
  int* col  = (int*)alloc((size_t)ET*4);
  int* flag = (int*)alloc(256);
  float* ws2 = (float*)alloc(1024*4);
  float* wd2 = (float*)alloc(1024*4);
  _Float16* Bp1 = (_Float16*)alloc((size_t)16384*2);
  _Float16* Bp  = (_Float16*)alloc((size_t)65536*2);

  dim3 b256(256);
  // launch 1: init + weight prep (independent block ranges)
  k_init_wprep<<<SCAN_NB + 324, b256, 0, stream>>>(ei, deg, cnt, flag,
                                                   W1, W2, as2, ad2,
                                                   Bp1, Bp, ws2, wd2);
  // launch 2: degree atomics || layer-1 GEMM (independent, overlapped)
  k_deg_gemm1<<<NB_DEG + NB_GEMM1, b256, 0, stream>>>(ei, deg, flag,
                                                      x, Bp1, h1, as1, ad1,
                                                      als1, ald1);
  // launch 3: single-pass scan (replaces part/carry/add chain)
  k_scan<<<SCAN_NB, b256, 0, stream>>>(deg, row_ptr);
  // launch 4: CSR fill
  k_fill<<<(ET+255)/256, b256, 0, stream>>>(ei, row_ptr, cnt, col, flag);
  // launch 5: layer 1 softmax+agg (alpha2 fused)
  k_attn_agg1<<<N_NODES/4, b256, 0, stream>>>(h1, als1, ald1, row_ptr, col,
                                              b1, hr, ws2, wd2, als2, ald2);
  // launch 6: layer 2 fused softmax+agg+output-GEMM
  k_attn_agg2<<<N_NODES/16, dim3(1024), 0, stream>>>(hr, als2, ald2, row_ptr, col,
                                                     Bp, b2, outp);
}

// Round 10
// 323.473 us; speedup vs baseline: 1.0836x; 1.0595x over previous
//
#include <hip/hip_runtime.h>

#define N_NODES 50000
#define N_EDGES 800000
#define ET (N_EDGES + N_NODES)   // 850000 incl. self loops
#define HEADS 8
#define NPAD 50048               // 782 blocks * 64 nodes
#define SCAN_NB 196              // ceil(50000/256)
#define CAP 96                   // LDS-cached edges per node (deg>CAP -> recompute)
#define LRS 1032                 // LDS A-tile row stride (halves, 16B-aligned)
#define NB_DEG 3321              // ceil(850000/256)
#define NB_GEMM1 782             // NPAD/64

typedef __attribute__((ext_vector_type(8))) _Float16 half8;
typedef __attribute__((ext_vector_type(2))) _Float16 half2v;
typedef __attribute__((ext_vector_type(4))) float f32x4;

// wave-local LDS fence: drains this wave's outstanding DS ops (same-wave
// cross-lane LDS write->read; consumers are ds_reads, ordered by "memory").
__device__ __forceinline__ void wave_lds_fence(){
  asm volatile("s_waitcnt lgkmcnt(0)" ::: "memory");
}

__device__ __forceinline__ int edge_src(const int* ei, int e, int is64){
  if (e >= N_EDGES) return e - N_EDGES;          // self loop
  return is64 ? ei[2*e] : ei[e];
}
__device__ __forceinline__ int edge_dst(const int* ei, int e, int is64){
  if (e >= N_EDGES) return e - N_EDGES;          // self loop
  return is64 ? ei[2*(N_EDGES + e)] : ei[N_EDGES + e];
}

// ======== launch 1: init (zero deg/cnt + layout probe) FUSED with wprep ========
// blocks [0,196): init; [196,452): W2 pack; [452,516): W1 pack; [516,520): wtilde
__global__ void k_init_wprep(const int* __restrict__ ei, int* __restrict__ deg,
                             int* __restrict__ cnt, int* __restrict__ flag,
                             const float* __restrict__ W1, const float* __restrict__ W2,
                             const float* __restrict__ as2, const float* __restrict__ ad2,
                             _Float16* __restrict__ Bp1, _Float16* __restrict__ Bp,
                             float* __restrict__ ws2, float* __restrict__ wd2){
  int b = blockIdx.x;
  int t_ = threadIdx.x;
  if (b < SCAN_NB){
    int i = b*256 + t_;
    if (i < N_NODES){ deg[i] = 0; cnt[i] = 0; }
    if (i == 0){
      int zeros = 0;
      for (int k = 0; k < 64; k++){
        if (ei[2*k + 1] == 0) zeros++;
      }
      *flag = (zeros >= 60) ? 1 : 0;   // 1 => int64 little-endian layout
    }
  } else if (b < SCAN_NB + 256){
    int t = (b - SCAN_NB)*256 + t_;
    int j = t & 7, lane = (t >> 3) & 63, nt = (t >> 9) & 3, kt = t >> 11;
    int k = kt*32 + (lane >> 4)*8 + j;
    int c = nt*16 + (lane & 15);
    int h = k >> 7, kk = k & 127;
    Bp[t] = (_Float16)(0.125f * W2[kk*512 + h*64 + c]);
  } else if (b < SCAN_NB + 320){
    int t = (b - SCAN_NB - 256)*256 + t_;
    int j = t & 7, lane = (t >> 3) & 63, nt = (t >> 9) & 7, kt = t >> 12;
    int k = kt*32 + (lane >> 4)*8 + j;
    int c = nt*16 + (lane & 15);
    Bp1[t] = (_Float16)W1[k*128 + c];
  } else {
    int t = (b - SCAN_NB - 320)*256 + t_;
    int k = t >> 3, h = t & 7;
    float s = 0.f, d = 0.f;
    for (int dd = 0; dd < 64; dd++){
      float w = W2[k*512 + h*64 + dd];
      s += w * as2[h*64 + dd];
      d += w * ad2[h*64 + dd];
    }
    ws2[h*128 + k] = s;
    wd2[h*128 + k] = d;
  }
}

// ======== launch 2: degree histogram FUSED with layer-1 GEMM (independent) ========
// blocks [0,NB_DEG): degree atomics; [NB_DEG, NB_DEG+NB_GEMM1): h1 = x@W1 + alpha1.
__global__ void __launch_bounds__(256) k_deg_gemm1(
    const int* __restrict__ ei, int* __restrict__ deg, const int* __restrict__ flag,
    const float* __restrict__ x, const _Float16* __restrict__ Bp1,
    _Float16* __restrict__ h1,
    const float* __restrict__ as1, const float* __restrict__ ad1,
    float* __restrict__ als1, float* __restrict__ ald1){
  if (blockIdx.x < NB_DEG){
    int e = blockIdx.x*blockDim.x + threadIdx.x;
    if (e >= ET) return;
    int is64 = *flag;
    int d = edge_dst(ei, e, is64);
    atomicAdd(&deg[d], 1);
    return;
  }
  int bid = blockIdx.x - NB_DEG;
  int tid = threadIdx.x;
  int lane = tid & 63, wv = tid >> 6;
  int n0 = bid*64 + wv*16;
  int rowA = n0 + (lane & 15);
  int koff = (lane >> 4)*8;
  const float* xr = x + (size_t)rowA*128 + koff;
  f32x4 acc[8];
  #pragma unroll
  for (int i = 0; i < 8; i++) acc[i] = (f32x4){0.f,0.f,0.f,0.f};
  bool inb = (rowA < N_NODES);
  #pragma unroll
  for (int kt = 0; kt < 4; kt++){
    half8 af;
    if (inb){
      float4 a0 = *(const float4*)(xr + kt*32);
      float4 a1 = *(const float4*)(xr + kt*32 + 4);
      af = (half8){(_Float16)a0.x,(_Float16)a0.y,(_Float16)a0.z,(_Float16)a0.w,
                   (_Float16)a1.x,(_Float16)a1.y,(_Float16)a1.z,(_Float16)a1.w};
    } else {
      af = (half8){0,0,0,0,0,0,0,0};
    }
    #pragma unroll
    for (int nt = 0; nt < 8; nt++){
      half8 bf = *(const half8*)(Bp1 + (((kt*8 + nt)*64 + lane) << 3));
      acc[nt] = __builtin_amdgcn_mfma_f32_16x16x32_f16(af, bf, acc[nt], 0, 0, 0);
    }
  }
  int m = lane & 15, q = lane >> 4;
  int r0 = n0 + q*4;               // C/D: col=lane&15, row=(lane>>4)*4+reg  [m89]
  #pragma unroll
  for (int nt = 0; nt < 8; nt++){
    int c = nt*16 + m;
    #pragma unroll
    for (int r = 0; r < 4; r++){
      int n = r0 + r;
      if (n < N_NODES) h1[(size_t)n*128 + c] = (_Float16)acc[nt][r];
    }
  }
  // fused alpha1: lane's acc[nt][r] is channel (nt*16+m) == head nt, pos m of row r0+r
  float as1v[8], ad1v[8];
  #pragma unroll
  for (int nt = 0; nt < 8; nt++){
    as1v[nt] = as1[nt*16 + m];
    ad1v[nt] = ad1[nt*16 + m];
  }
  #pragma unroll
  for (int r = 0; r < 4; r++){
    float vs[8], vd[8];
    #pragma unroll
    for (int nt = 0; nt < 8; nt++){
      vs[nt] = acc[nt][r]*as1v[nt];
      vd[nt] = acc[nt][r]*ad1v[nt];
      #pragma unroll
      for (int off = 1; off < 16; off <<= 1){
        vs[nt] += __shfl_xor(vs[nt], off, 64);
        vd[nt] += __shfl_xor(vd[nt], off, 64);
      }
    }
    int n = r0 + r;
    if (m == r && n < N_NODES){
      float4 v0; v0.x = vs[0]; v0.y = vs[1]; v0.z = vs[2]; v0.w = vs[3];
      float4 v1; v1.x = vs[4]; v1.y = vs[5]; v1.z = vs[6]; v1.w = vs[7];
      float4 w0; w0.x = vd[0]; w0.y = vd[1]; w0.z = vd[2]; w0.w = vd[3];
      float4 w1; w1.x = vd[4]; w1.y = vd[5]; w1.z = vd[6]; w1.w = vd[7];
      *(float4*)&als1[n*8]     = v0;
      *(float4*)&als1[n*8 + 4] = v1;
      *(float4*)&ald1[n*8]     = w0;
      *(float4*)&ald1[n*8 + 4] = w1;
    }
  }
}

// ---- 3-stage scan (R7 form - measured faster than single-pass brute force) ----
__global__ void k_scan_part(const int* __restrict__ deg, int* __restrict__ loc,
                            int* __restrict__ part){
  __shared__ int lds[256];
  int t = threadIdx.x, i = blockIdx.x*256 + t;
  int v = (i < N_NODES) ? deg[i] : 0;
  lds[t] = v;
  __syncthreads();
  for (int off = 1; off < 256; off <<= 1){
    int x = (t >= off) ? lds[t - off] : 0;
    __syncthreads();
    lds[t] += x;
    __syncthreads();
  }
  if (i < N_NODES) loc[i] = lds[t] - v;          // local exclusive
  if (t == 255) part[blockIdx.x] = lds[255];
}

__global__ void k_scan_carry(int* __restrict__ part, int* __restrict__ carry){
  __shared__ int lds[256];
  int t = threadIdx.x;
  int v = (t < SCAN_NB) ? part[t] : 0;
  lds[t] = v;
  __syncthreads();
  for (int off = 1; off < 256; off <<= 1){
    int x = (t >= off) ? lds[t - off] : 0;
    __syncthreads();
    lds[t] += x;
    __syncthreads();
  }
  if (t < SCAN_NB) carry[t] = lds[t] - v;        // exclusive over blocks
}

__global__ void k_scan_add(const int* __restrict__ loc, const int* __restrict__ carry,
                           int* __restrict__ row_ptr){
  int i = blockIdx.x*blockDim.x + threadIdx.x;
  if (i < N_NODES) row_ptr[i] = loc[i] + carry[i >> 8];
  if (i == 0) row_ptr[N_NODES] = ET;
}

__global__ void k_fill(const int* __restrict__ ei, const int* __restrict__ row_ptr,
                       int* __restrict__ cnt, int* __restrict__ col,
                       const int* __restrict__ flag){
  int e = blockIdx.x*blockDim.x + threadIdx.x;
  if (e >= ET) return;
  int is64 = *flag;
  int s = edge_src(ei, e, is64);
  int d = edge_dst(ei, e, is64);
  int pos = atomicAdd(&cnt[d], 1);
  col[row_ptr[d] + pos] = s;
}

// ===== layer 1: two-phase softmax+agg; WIDE phase-2 gather, 2-stage pipeline =====
// Phase 2 lane map (eg=lane>>4, cb=lane&15): lane handles edge j+eg, channels
// [cb*8,cb*8+8). 2-stage SW pipeline: issue next group's gather before consuming
// current (doubles gathers in flight; explicit names so compiler keeps order).
__global__ void k_attn_agg1(const _Float16* __restrict__ h1,
    const float* __restrict__ als, const float* __restrict__ ald,
    const int* __restrict__ row_ptr, const int* __restrict__ col,
    const float* __restrict__ bias, _Float16* __restrict__ hr,
    const float* __restrict__ ws2, const float* __restrict__ wd2,
    float* __restrict__ als2, float* __restrict__ ald2){
  __shared__ _Float16 ew_s[4][CAP*8];
  __shared__ int col_s[4][CAP];
  __shared__ _Float16 ot_s[4][136];
  int tid = threadIdx.x;
  int wv = tid >> 6, lane = tid & 63;
  int n = blockIdx.x*4 + wv;              // grid exact: 12500*4 = 50000
  int beg = row_ptr[n], end = row_ptr[n+1];
  int deg = end - beg;
  int items = deg*8;
  int h = lane & 7;
  float ad = ald[n*8 + h];
  _Float16* es = ew_s[wv];
  int* cs = col_s[wv];
  float l = 0.f;
  int itc = items < CAP*8 ? items : CAP*8;
  int it = lane;
  for (; it < itc; it += 64){             // cached range: store es + col
    int e = it >> 3;
    int s = col[beg + e];
    float a = als[s*8 + h] + ad;
    a = (a > 0.f) ? a : 0.2f*a;
    float ex = __expf(a);
    es[it] = (_Float16)ex;
    if ((it & 7) == 0) cs[e] = s;
    l += ex;
  }
  for (; it < items; it += 64){           // rare overflow range
    int s = col[beg + (it >> 3)];
    float a = als[s*8 + h] + ad;
    a = (a > 0.f) ? a : 0.2f*a;
    l += __expf(a);
  }
  l += __shfl_xor(l, 8, 64);
  l += __shfl_xor(l, 16, 64);
  l += __shfl_xor(l, 32, 64);
  float inv = 1.f / (l + 1e-16f);
  wave_lds_fence();                       // own-wave LDS only: no __syncthreads
  // ---- phase 2: wide gather, 2-stage pipeline ----
  int eg = lane >> 4, cb = lane & 15;
  int hq = cb >> 1;                       // head owning channels cb*8..cb*8+7
  float invh = __shfl(inv, hq, 64);
  float adh  = __shfl(ad, hq, 64);        // ald[n*8+hq] (for overflow path)
  float acc[8];
  #pragma unroll
  for (int k = 0; k < 8; k++) acc[k] = 0.f;
  int degc = deg < CAP ? deg : CAP;
  int j = 0;
  half8 cv;
  if (j + 3 < degc){
    cv = *(const half8*)(h1 + (size_t)cs[j + eg]*128 + cb*8);
  }
  for (; j + 7 < degc; j += 4){
    half8 nv = *(const half8*)(h1 + (size_t)cs[j + 4 + eg]*128 + cb*8);
    float w = (float)es[(j + eg)*8 + hq] * invh;
    #pragma unroll
    for (int k = 0; k < 8; k++) acc[k] += w*(float)cv[k];
    cv = nv;
  }
  if (j + 3 < degc){                      // consume last preloaded group
    float w = (float)es[(j + eg)*8 + hq] * invh;
    #pragma unroll
    for (int k = 0; k < 8; k++) acc[k] += w*(float)cv[k];
    j += 4;
  }
  if (j < degc){                          // tail (predicated, <=3 edges)
    int e = j + eg;
    if (e < degc){
      int s = cs[e];
      float w = (float)es[e*8 + hq] * invh;
      half8 v = *(const half8*)(h1 + (size_t)s*128 + cb*8);
      #pragma unroll
      for (int k = 0; k < 8; k++) acc[k] += w*(float)v[k];
    }
  }
  for (int jj = degc; jj < deg; jj += 4){ // rare: deg > CAP, recompute weights
    int e = jj + eg;
    if (e < deg){
      int s = col[beg + e];
      float a = als[s*8 + hq] + adh;
      a = (a > 0.f) ? a : 0.2f*a;
      float w = __expf(a)*invh;
      half8 v = *(const half8*)(h1 + (size_t)s*128 + cb*8);
      #pragma unroll
      for (int k = 0; k < 8; k++) acc[k] += w*(float)v[k];
    }
  }
  // cross-eg reduce (4 edge groups)
  #pragma unroll
  for (int k = 0; k < 8; k++){
    acc[k] += __shfl_xor(acc[k], 16, 64);
    acc[k] += __shfl_xor(acc[k], 32, 64);
  }
  // bias + ReLU; lanes eg==0 write the full row (16 lanes x 16B, coalesced)
  float4 b0 = *(const float4*)(bias + cb*8);
  float4 b1 = *(const float4*)(bias + cb*8 + 4);
  float bb[8] = {b0.x,b0.y,b0.z,b0.w,b1.x,b1.y,b1.z,b1.w};
  half8 oh;
  #pragma unroll
  for (int k = 0; k < 8; k++) oh[k] = (_Float16)fmaxf(acc[k] + bb[k], 0.f);
  if (eg == 0){
    *(half8*)(hr + (size_t)n*128 + cb*8) = oh;
    ((half8*)&ot_s[wv][0])[cb] = oh;      // same-wave LDS transpose staging
  }
  wave_lds_fence();
  // fused alpha2: lane -> (head hh=lane>>3, segment seg=lane&7)
  int hh = lane >> 3, seg = lane & 7;
  const half2v* otp = (const half2v*)&ot_s[wv][0];
  const float* wsr = ws2 + hh*128 + seg*16;
  const float* wdr = wd2 + hh*128 + seg*16;
  float vs = 0.f, vd = 0.f;
  #pragma unroll
  for (int i = 0; i < 8; i++){
    half2v v = otp[seg*8 + i];
    float vx = (float)v.x, vy = (float)v.y;
    vs += vx*wsr[2*i] + vy*wsr[2*i + 1];
    vd += vx*wdr[2*i] + vy*wdr[2*i + 1];
  }
  vs += __shfl_xor(vs, 1, 64); vd += __shfl_xor(vd, 1, 64);
  vs += __shfl_xor(vs, 2, 64); vd += __shfl_xor(vd, 2, 64);
  vs += __shfl_xor(vs, 4, 64); vd += __shfl_xor(vd, 4, 64);
  if (seg == 0){
    als2[n*8 + hh] = vs;
    ald2[n*8 + hh] = vd;
  }
}

// ===== layer 2 FUSED: softmax+agg (16 waves = 16 nodes) + output MFMA GEMM =====
// R7 structure (two-phase LDS exp table, (hp,cb) gather) + 2-stage pipeline:
// next 4-edge group's gathers issue before current group's FMAs (8 gathers in
// flight, +16 VGPR -> ~50 total, still 2 blocks/CU). No launch_bounds cap that
// would force spill (R8 lesson); no unroll-8 all-live pattern (R5 lesson).
__global__ void __launch_bounds__(1024) k_attn_agg2(const _Float16* __restrict__ hr,
    const float* __restrict__ als, const float* __restrict__ ald,
    const int* __restrict__ row_ptr, const int* __restrict__ col,
    const _Float16* __restrict__ Bp, const float* __restrict__ b2,
    float* __restrict__ outp){
  __shared__ _Float16 ew_s[16][CAP*8];
  __shared__ int col_s[16][CAP];
  __shared__ _Float16 at[16*LRS];
  int tid = threadIdx.x;
  int wv = tid >> 6, lane = tid & 63;
  int n = blockIdx.x*16 + wv;             // grid exact: 3125*16 = 50000
  int beg = row_ptr[n], end = row_ptr[n+1];
  int deg = end - beg;
  int items = deg*8;
  int h = lane & 7;
  float ad = ald[n*8 + h];
  _Float16* es = ew_s[wv];
  int* cs = col_s[wv];
  float l = 0.f;
  int itc = items < CAP*8 ? items : CAP*8;
  int it = lane;
  for (; it < itc; it += 64){
    int e = it >> 3;
    int s = col[beg + e];
    float a = als[s*8 + h] + ad;
    a = (a > 0.f) ? a : 0.2f*a;
    float ex = __expf(a);
    es[it] = (_Float16)ex;
    if ((it & 7) == 0) cs[e] = s;
    l += ex;
  }
  for (; it < items; it += 64){
    int s = col[beg + (it >> 3)];
    float a = als[s*8 + h] + ad;
    a = (a > 0.f) ? a : 0.2f*a;
    l += __expf(a);
  }
  l += __shfl_xor(l, 8, 64);
  l += __shfl_xor(l, 16, 64);
  l += __shfl_xor(l, 32, 64);
  float inv = 1.f / (l + 1e-16f);   // for head lane&7 (lanes with same lane&7 agree)
  wave_lds_fence();                 // own-wave LDS only: no cross-wave barrier here
  int hp = lane >> 4, cb = lane & 15;
  float invA = __shfl(inv, 2*hp, 64);       // inv for head 2hp   (held by lane 2hp)
  float invB = __shfl(inv, 2*hp + 1, 64);   // inv for head 2hp+1
  half2v inv2; inv2.x = (_Float16)invA; inv2.y = (_Float16)invB;
  half2v acc_a[4], acc_b[4];
  #pragma unroll
  for (int i = 0; i < 4; i++){
    acc_a[i] = (half2v){(_Float16)0.f, (_Float16)0.f};
    acc_b[i] = (half2v){(_Float16)0.f, (_Float16)0.f};
  }
  int degc = deg < CAP ? deg : CAP;
  const _Float16* esw = es + 2*hp;          // per-lane weight base (both heads, u32)
  int j = 0;
  half8 cv0, cv1, cv2, cv3;
  if (j + 3 < degc){                        // prologue: load group 0
    cv0 = *(const half8*)(hr + (size_t)cs[j+0]*128 + cb*8);
    cv1 = *(const half8*)(hr + (size_t)cs[j+1]*128 + cb*8);
    cv2 = *(const half8*)(hr + (size_t)cs[j+2]*128 + cb*8);
    cv3 = *(const half8*)(hr + (size_t)cs[j+3]*128 + cb*8);
  }
  for (; j + 7 < degc; j += 4){
    // issue NEXT group's gathers first (hides L2/L3 latency under the FMAs)
    half8 nv0 = *(const half8*)(hr + (size_t)cs[j+4]*128 + cb*8);
    half8 nv1 = *(const half8*)(hr + (size_t)cs[j+5]*128 + cb*8);
    half8 nv2 = *(const half8*)(hr + (size_t)cs[j+6]*128 + cb*8);
    half8 nv3 = *(const half8*)(hr + (size_t)cs[j+7]*128 + cb*8);
    half2v w0 = *(const half2v*)(esw + (j+0)*8) * inv2;
    half2v w1 = *(const half2v*)(esw + (j+1)*8) * inv2;
    half2v w2 = *(const half2v*)(esw + (j+2)*8) * inv2;
    half2v w3 = *(const half2v*)(esw + (j+3)*8) * inv2;
    #pragma unroll
    for (int k = 0; k < 4; k++){
      half2v t;
      t = (half2v){cv0[2*k], cv0[2*k+1]};
      acc_a[k] += (half2v){w0.x, w0.x} * t;
      acc_b[k] += (half2v){w0.y, w0.y} * t;
      t = (half2v){cv1[2*k], cv1[2*k+1]};
      acc_a[k] += (half2v){w1.x, w1.x} * t;
      acc_b[k] += (half2v){w1.y, w1.y} * t;
      t = (half2v){cv2[2*k], cv2[2*k+1]};
      acc_a[k] += (half2v){w2.x, w2.x} * t;
      acc_b[k] += (half2v){w2.y, w2.y} * t;
      t = (half2v){cv3[2*k], cv3[2*k+1]};
      acc_a[k] += (half2v){w3.x, w3.x} * t;
      acc_b[k] += (half2v){w3.y, w3.y} * t;
    }
    cv0 = nv0; cv1 = nv1; cv2 = nv2; cv3 = nv3;
  }
  if (j + 3 < degc){                        // epilogue: consume last full group
    half2v w0 = *(const half2v*)(esw + (j+0)*8) * inv2;
    half2v w1 = *(const half2v*)(esw + (j+1)*8) * inv2;
    half2v w2 = *(const half2v*)(esw + (j+2)*8) * inv2;
    half2v w3 = *(const half2v*)(esw + (j+3)*8) * inv2;
    #pragma unroll
    for (int k = 0; k < 4; k++){
      half2v t;
      t = (half2v){cv0[2*k], cv0[2*k+1]};
      acc_a[k] += (half2v){w0.x, w0.x} * t;
      acc_b[k] += (half2v){w0.y, w0.y} * t;
      t = (half2v){cv1[2*k], cv1[2*k+1]};
      acc_a[k] += (half2v){w1.x, w1.x} * t;
      acc_b[k] += (half2v){w1.y, w1.y} * t;
      t = (half2v){cv2[2*k], cv2[2*k+1]};
      acc_a[k] += (half2v){w2.x, w2.x} * t;
      acc_b[k] += (half2v){w2.y, w2.y} * t;
      t = (half2v){cv3[2*k], cv3[2*k+1]};
      acc_a[k] += (half2v){w3.x, w3.x} * t;
      acc_b[k] += (half2v){w3.y, w3.y} * t;
    }
    j += 4;
  }
  for (; j < degc; j++){
    int s = cs[j];
    half2v w = *(const half2v*)(esw + j*8) * inv2;
    half8 v = *(const half8*)(hr + (size_t)s*128 + cb*8);
    #pragma unroll
    for (int k = 0; k < 4; k++){
      half2v t = (half2v){v[2*k], v[2*k+1]};
      acc_a[k] += (half2v){w.x, w.x} * t;
      acc_b[k] += (half2v){w.y, w.y} * t;
    }
  }
  if (deg > CAP){                             // rare: deg > CAP, recompute weights
    float2 adv = *(const float2*)(ald + (size_t)n*8 + 2*hp);
    for (; j < deg; j++){
      int s = col[beg + j];
      float2 alv = *(const float2*)(als + (size_t)s*8 + 2*hp);
      float a0 = alv.x + adv.x; a0 = (a0 > 0.f) ? a0 : 0.2f*a0;
      float a1 = alv.y + adv.y; a1 = (a1 > 0.f) ? a1 : 0.2f*a1;
      _Float16 w0 = (_Float16)(__expf(a0)*invA);
      _Float16 w1 = (_Float16)(__expf(a1)*invB);
      half8 v = *(const half8*)(hr + (size_t)s*128 + cb*8);
      #pragma unroll
      for (int k = 0; k < 4; k++){
        half2v t = (half2v){v[2*k], v[2*k+1]};
        acc_a[k] += (half2v){w0, w0} * t;
        acc_b[k] += (half2v){w1, w1} * t;
      }
    }
  }
  // write normalized rows into the LDS A-tile: head 2hp and 2hp+1, channels cb*8..
  _Float16* ar = at + wv*LRS + (2*hp)*128 + cb*8;
  half8 oa, ob;
  #pragma unroll
  for (int k = 0; k < 4; k++){
    oa[2*k] = acc_a[k].x; oa[2*k+1] = acc_a[k].y;
    ob[2*k] = acc_b[k].x; ob[2*k+1] = acc_b[k].y;
  }
  *(half8*)ar = oa;
  *(half8*)(ar + 128) = ob;
  __syncthreads();
  if (wv >= 4) return;
  // MFMA epilogue: wave wv = output col-tile nt; A from LDS, Bp L2-hot
  int m = lane & 15, q = lane >> 4;
  const _Float16* arow = at + m*LRS + q*8;
  f32x4 cacc = (f32x4){0.f,0.f,0.f,0.f};
  #pragma unroll 4
  for (int kt = 0; kt < 32; kt++){
    half8 af = *(const half8*)(arow + kt*32);
    half8 bf = *(const half8*)(Bp + (((kt*4 + wv)*64 + lane) << 3));
    cacc = __builtin_amdgcn_mfma_f32_16x16x32_f16(af, bf, cacc, 0, 0, 0);
  }
  int c = wv*16 + m;
  float bb = b2[c];
  #pragma unroll
  for (int r = 0; r < 4; r++){
    int nrow = blockIdx.x*16 + q*4 + r;   // C/D: col=lane&15, row=(lane>>4)*4+reg [m89]
    outp[(size_t)nrow*64 + c] = cacc[r] + bb;
  }
}

extern "C" void kernel_launch(void* const* d_in, const int* in_sizes, int n_in,
                              void* d_out, int out_size, void* d_ws, size_t ws_size,
                              hipStream_t stream){
  const float* x   = (const float*)d_in[0];
  const int*   ei  = (const int*)d_in[1];
  const float* W1  = (const float*)d_in[2];
  const float* as1 = (const float*)d_in[3];
  const float* ad1 = (const float*)d_in[4];
  const float* b1  = (const float*)d_in[5];
  const float* W2  = (const float*)d_in[6];
  const float* as2 = (const float*)d_in[7];
  const float* ad2 = (const float*)d_in[8];
  const float* b2  = (const float*)d_in[9];
  float* outp = (float*)d_out;

  char* p = (char*)d_ws;
  auto alloc = [&](size_t bytes) -> void* {
    void* r = (void*)p;
    p += (bytes + 255) & ~(size_t)255;
    return r;
  };
  _Float16* h1  = (_Float16*)alloc((size_t)NPAD*128*2);          // [N,128] fp16
  _Float16* hr  = (_Float16*)alloc((size_t)N_NODES*128*2);       // [N,128] fp16
  float* als1 = (float*)alloc((size_t)N_NODES*8*4);
  float* ald1 = (float*)alloc((size_t)N_NODES*8*4);
  float* als2 = (float*)alloc((size_t)N_NODES*8*4);
  float* ald2 = (float*)alloc((size_t)N_NODES*8*4);
  int* row_ptr = (int*)alloc((size_t)(N_NODES+1)*4);
  int* deg  = (int*)alloc((size_t)N_NODES*4);
  int* cnt  = (int*)alloc((size_t)N_NODES*4);
  int* col  = (int*)alloc((size_t)ET*4);
  int* loc  = (int*)alloc((size_t)N_NODES*4);
  int* part = (int*)alloc(256*4);
  int* carry= (int*)alloc(256*4);
  int* flag = (int*)alloc(256);
  float* ws2 = (float*)alloc(1024*4);
  float* wd2 = (float*)alloc(1024*4);
  _Float16* Bp1 = (_Float16*)alloc((size_t)16384*2);
  _Float16* Bp  = (_Float16*)alloc((size_t)65536*2);

  dim3 b256(256);
  // launch 1: init + weight prep (independent block ranges)
  k_init_wprep<<<SCAN_NB + 324, b256, 0, stream>>>(ei, deg, cnt, flag,
                                                   W1, W2, as2, ad2,
                                                   Bp1, Bp, ws2, wd2);
  // launch 2: degree atomics || layer-1 GEMM (independent, overlapped)
  k_deg_gemm1<<<NB_DEG + NB_GEMM1, b256, 0, stream>>>(ei, deg, flag,
                                                      x, Bp1, h1, as1, ad1,
                                                      als1, ald1);
  // CSR scan + fill (3-launch chain - R7 measured form)
  k_scan_part<<<SCAN_NB, b256, 0, stream>>>(deg, loc, part);
  k_scan_carry<<<1, b256, 0, stream>>>(part, carry);
  k_scan_add<<<SCAN_NB, b256, 0, stream>>>(loc, carry, row_ptr);
  k_fill<<<(ET+255)/256, b256, 0, stream>>>(ei, row_ptr, cnt, col, flag);
  // layer 1 softmax+agg (alpha2 fused)
  k_attn_agg1<<<N_NODES/4, b256, 0, stream>>>(h1, als1, ald1, row_ptr, col,
                                              b1, hr, ws2, wd2, als2, ald2);
  // layer 2: fused softmax+agg+output-GEMM
  k_attn_agg2<<<N_NODES/16, dim3(1024), 0, stream>>>(hr, als2, ald2, row_ptr, col,
                                                     Bp, b2, outp);
}

// Round 11
// 322.268 us; speedup vs baseline: 1.0877x; 1.0037x over previous
//
#include <hip/hip_runtime.h>

#define N_NODES 50000
#define N_EDGES 800000
#define ET (N_EDGES + N_NODES)   // 850000 incl. self loops
#define HEADS 8
#define NPAD 50048               // 782 blocks * 64 nodes
#define SCAN_NB 196              // ceil(50000/256)
#define CAP 96                   // LDS-cached edges per node (deg>CAP -> recompute)
#define LRS 1032                 // LDS A-tile row stride (halves, 16B-aligned)
#define NB_DEG 3321              // ceil(850000/256)
#define NB_GEMM1 782             // NPAD/64

typedef __attribute__((ext_vector_type(8))) _Float16 half8;
typedef __attribute__((ext_vector_type(2))) _Float16 half2v;
typedef __attribute__((ext_vector_type(4))) float f32x4;

// wave-local LDS fence: drains this wave's outstanding DS ops (same-wave
// cross-lane LDS write->read; consumers are ds_reads, ordered by "memory").
__device__ __forceinline__ void wave_lds_fence(){
  asm volatile("s_waitcnt lgkmcnt(0)" ::: "memory");
}

__device__ __forceinline__ int edge_src(const int* ei, int e, int is64){
  if (e >= N_EDGES) return e - N_EDGES;          // self loop
  return is64 ? ei[2*e] : ei[e];
}
__device__ __forceinline__ int edge_dst(const int* ei, int e, int is64){
  if (e >= N_EDGES) return e - N_EDGES;          // self loop
  return is64 ? ei[2*(N_EDGES + e)] : ei[N_EDGES + e];
}

// ======== launch 1: init (zero deg/cnt + layout probe) FUSED with wprep ========
// blocks [0,196): init; [196,452): W2 pack; [452,516): W1 pack; [516,520): wtilde
__global__ void k_init_wprep(const int* __restrict__ ei, int* __restrict__ deg,
                             int* __restrict__ cnt, int* __restrict__ flag,
                             const float* __restrict__ W1, const float* __restrict__ W2,
                             const float* __restrict__ as2, const float* __restrict__ ad2,
                             _Float16* __restrict__ Bp1, _Float16* __restrict__ Bp,
                             float* __restrict__ ws2, float* __restrict__ wd2){
  int b = blockIdx.x;
  int t_ = threadIdx.x;
  if (b < SCAN_NB){
    int i = b*256 + t_;
    if (i < N_NODES){ deg[i] = 0; cnt[i] = 0; }
    if (i == 0){
      int zeros = 0;
      for (int k = 0; k < 64; k++){
        if (ei[2*k + 1] == 0) zeros++;
      }
      *flag = (zeros >= 60) ? 1 : 0;   // 1 => int64 little-endian layout
    }
  } else if (b < SCAN_NB + 256){
    int t = (b - SCAN_NB)*256 + t_;
    int j = t & 7, lane = (t >> 3) & 63, nt = (t >> 9) & 3, kt = t >> 11;
    int k = kt*32 + (lane >> 4)*8 + j;
    int c = nt*16 + (lane & 15);
    int h = k >> 7, kk = k & 127;
    Bp[t] = (_Float16)(0.125f * W2[kk*512 + h*64 + c]);
  } else if (b < SCAN_NB + 320){
    int t = (b - SCAN_NB - 256)*256 + t_;
    int j = t & 7, lane = (t >> 3) & 63, nt = (t >> 9) & 7, kt = t >> 12;
    int k = kt*32 + (lane >> 4)*8 + j;
    int c = nt*16 + (lane & 15);
    Bp1[t] = (_Float16)W1[k*128 + c];
  } else {
    int t = (b - SCAN_NB - 320)*256 + t_;
    int k = t >> 3, h = t & 7;
    float s = 0.f, d = 0.f;
    for (int dd = 0; dd < 64; dd++){
      float w = W2[k*512 + h*64 + dd];
      s += w * as2[h*64 + dd];
      d += w * ad2[h*64 + dd];
    }
    ws2[h*128 + k] = s;
    wd2[h*128 + k] = d;
  }
}

// ======== launch 2: degree histogram FUSED with layer-1 GEMM (independent) ========
// blocks [0,NB_DEG): degree atomics; [NB_DEG, NB_DEG+NB_GEMM1): h1 = x@W1 + alpha1.
__global__ void __launch_bounds__(256) k_deg_gemm1(
    const int* __restrict__ ei, int* __restrict__ deg, const int* __restrict__ flag,
    const float* __restrict__ x, const _Float16* __restrict__ Bp1,
    _Float16* __restrict__ h1,
    const float* __restrict__ as1, const float* __restrict__ ad1,
    float* __restrict__ als1, float* __restrict__ ald1){
  if (blockIdx.x < NB_DEG){
    int e = blockIdx.x*blockDim.x + threadIdx.x;
    if (e >= ET) return;
    int is64 = *flag;
    int d = edge_dst(ei, e, is64);
    atomicAdd(&deg[d], 1);
    return;
  }
  int bid = blockIdx.x - NB_DEG;
  int tid = threadIdx.x;
  int lane = tid & 63, wv = tid >> 6;
  int n0 = bid*64 + wv*16;
  int rowA = n0 + (lane & 15);
  int koff = (lane >> 4)*8;
  const float* xr = x + (size_t)rowA*128 + koff;
  f32x4 acc[8];
  #pragma unroll
  for (int i = 0; i < 8; i++) acc[i] = (f32x4){0.f,0.f,0.f,0.f};
  bool inb = (rowA < N_NODES);
  #pragma unroll
  for (int kt = 0; kt < 4; kt++){
    half8 af;
    if (inb){
      float4 a0 = *(const float4*)(xr + kt*32);
      float4 a1 = *(const float4*)(xr + kt*32 + 4);
      af = (half8){(_Float16)a0.x,(_Float16)a0.y,(_Float16)a0.z,(_Float16)a0.w,
                   (_Float16)a1.x,(_Float16)a1.y,(_Float16)a1.z,(_Float16)a1.w};
    } else {
      af = (half8){0,0,0,0,0,0,0,0};
    }
    #pragma unroll
    for (int nt = 0; nt < 8; nt++){
      half8 bf = *(const half8*)(Bp1 + (((kt*8 + nt)*64 + lane) << 3));
      acc[nt] = __builtin_amdgcn_mfma_f32_16x16x32_f16(af, bf, acc[nt], 0, 0, 0);
    }
  }
  int m = lane & 15, q = lane >> 4;
  int r0 = n0 + q*4;               // C/D: col=lane&15, row=(lane>>4)*4+reg  [m89]
  #pragma unroll
  for (int nt = 0; nt < 8; nt++){
    int c = nt*16 + m;
    #pragma unroll
    for (int r = 0; r < 4; r++){
      int n = r0 + r;
      if (n < N_NODES) h1[(size_t)n*128 + c] = (_Float16)acc[nt][r];
    }
  }
  // fused alpha1: lane's acc[nt][r] is channel (nt*16+m) == head nt, pos m of row r0+r
  float as1v[8], ad1v[8];
  #pragma unroll
  for (int nt = 0; nt < 8; nt++){
    as1v[nt] = as1[nt*16 + m];
    ad1v[nt] = ad1[nt*16 + m];
  }
  #pragma unroll
  for (int r = 0; r < 4; r++){
    float vs[8], vd[8];
    #pragma unroll
    for (int nt = 0; nt < 8; nt++){
      vs[nt] = acc[nt][r]*as1v[nt];
      vd[nt] = acc[nt][r]*ad1v[nt];
      #pragma unroll
      for (int off = 1; off < 16; off <<= 1){
        vs[nt] += __shfl_xor(vs[nt], off, 64);
        vd[nt] += __shfl_xor(vd[nt], off, 64);
      }
    }
    int n = r0 + r;
    if (m == r && n < N_NODES){
      float4 v0; v0.x = vs[0]; v0.y = vs[1]; v0.z = vs[2]; v0.w = vs[3];
      float4 v1; v1.x = vs[4]; v1.y = vs[5]; v1.z = vs[6]; v1.w = vs[7];
      float4 w0; w0.x = vd[0]; w0.y = vd[1]; w0.z = vd[2]; w0.w = vd[3];
      float4 w1; w1.x = vd[4]; w1.y = vd[5]; w1.z = vd[6]; w1.w = vd[7];
      *(float4*)&als1[n*8]     = v0;
      *(float4*)&als1[n*8 + 4] = v1;
      *(float4*)&ald1[n*8]     = w0;
      *(float4*)&ald1[n*8 + 4] = w1;
    }
  }
}

// ---- 3-stage scan (R7 form) ----
__global__ void k_scan_part(const int* __restrict__ deg, int* __restrict__ loc,
                            int* __restrict__ part){
  __shared__ int lds[256];
  int t = threadIdx.x, i = blockIdx.x*256 + t;
  int v = (i < N_NODES) ? deg[i] : 0;
  lds[t] = v;
  __syncthreads();
  for (int off = 1; off < 256; off <<= 1){
    int x = (t >= off) ? lds[t - off] : 0;
    __syncthreads();
    lds[t] += x;
    __syncthreads();
  }
  if (i < N_NODES) loc[i] = lds[t] - v;          // local exclusive
  if (t == 255) part[blockIdx.x] = lds[255];
}

__global__ void k_scan_carry(int* __restrict__ part, int* __restrict__ carry){
  __shared__ int lds[256];
  int t = threadIdx.x;
  int v = (t < SCAN_NB) ? part[t] : 0;
  lds[t] = v;
  __syncthreads();
  for (int off = 1; off < 256; off <<= 1){
    int x = (t >= off) ? lds[t - off] : 0;
    __syncthreads();
    lds[t] += x;
    __syncthreads();
  }
  if (t < SCAN_NB) carry[t] = lds[t] - v;        // exclusive over blocks
}

__global__ void k_scan_add(const int* __restrict__ loc, const int* __restrict__ carry,
                           int* __restrict__ row_ptr){
  int i = blockIdx.x*blockDim.x + threadIdx.x;
  if (i < N_NODES) row_ptr[i] = loc[i] + carry[i >> 8];
  if (i == 0) row_ptr[N_NODES] = ET;
}

// ---- CSR fill + layer-1 edge-weight precompute (hidden under atomic latency) ----
// Per edge: pos in CSR, col write, AND the 8 layer-1 attention weights
// w[h] = exp(leakyrelu(als1[s][h] + ald1[d][h])) stored as half8 at the CSR slot.
// Moves agg1's scattered als gather + 8 exps into this latency-bound kernel.
__global__ void k_fill(const int* __restrict__ ei, const int* __restrict__ row_ptr,
                       int* __restrict__ cnt, int* __restrict__ col,
                       const int* __restrict__ flag,
                       const float* __restrict__ als1, const float* __restrict__ ald1,
                       _Float16* __restrict__ ew1){
  int e = blockIdx.x*blockDim.x + threadIdx.x;
  if (e >= ET) return;
  int is64 = *flag;
  int s = edge_src(ei, e, is64);
  int d = edge_dst(ei, e, is64);
  int pos = atomicAdd(&cnt[d], 1);
  int slot = row_ptr[d] + pos;
  col[slot] = s;
  float4 a0 = *(const float4*)(als1 + (size_t)s*8);
  float4 a1 = *(const float4*)(als1 + (size_t)s*8 + 4);
  float4 d0 = *(const float4*)(ald1 + (size_t)d*8);
  float4 d1 = *(const float4*)(ald1 + (size_t)d*8 + 4);
  float av[8] = {a0.x+d0.x, a0.y+d0.y, a0.z+d0.z, a0.w+d0.w,
                 a1.x+d1.x, a1.y+d1.y, a1.z+d1.z, a1.w+d1.w};
  half8 w;
  #pragma unroll
  for (int h = 0; h < 8; h++){
    float a = av[h];
    a = (a > 0.f) ? a : 0.2f*a;
    w[h] = (_Float16)__expf(a);
  }
  *(half8*)(ew1 + (size_t)slot*8) = w;
}

// ===== layer 1: two-phase softmax+agg =====
// Phase 1: COALESCED contiguous read of precomputed ew1 weights (no scattered
// als gather, no exps) -> LDS es table + per-head sum. Phase 2: R7 wide gather
// (eg=lane>>4, cb=lane&15), fp32 acc, cross-eg shfl reduce. Wave-fence only.
__global__ void k_attn_agg1(const _Float16* __restrict__ h1,
    const _Float16* __restrict__ ew1,
    const int* __restrict__ row_ptr, const int* __restrict__ col,
    const float* __restrict__ bias, _Float16* __restrict__ hr,
    const float* __restrict__ ws2, const float* __restrict__ wd2,
    float* __restrict__ als2, float* __restrict__ ald2){
  __shared__ _Float16 ew_s[4][CAP*8];
  __shared__ int col_s[4][CAP];
  __shared__ _Float16 ot_s[4][136];
  int tid = threadIdx.x;
  int wv = tid >> 6, lane = tid & 63;
  int n = blockIdx.x*4 + wv;              // grid exact: 12500*4 = 50000
  int beg = row_ptr[n], end = row_ptr[n+1];
  int deg = end - beg;
  int items = deg*8;
  _Float16* es = ew_s[wv];
  int* cs = col_s[wv];
  const _Float16* ewr = ew1 + (size_t)beg*8;
  float l = 0.f;
  int itc = items < CAP*8 ? items : CAP*8;
  int it = lane;
  for (; it < itc; it += 64){             // coalesced: 64 lanes x 2B contiguous
    _Float16 w = ewr[it];
    es[it] = w;
    l += (float)w;
    if ((it & 7) == 0) cs[it >> 3] = col[beg + (it >> 3)];
  }
  for (; it < items; it += 64){           // rare overflow range
    l += (float)ewr[it];
  }
  l += __shfl_xor(l, 8, 64);
  l += __shfl_xor(l, 16, 64);
  l += __shfl_xor(l, 32, 64);
  float inv = 1.f / (l + 1e-16f);         // for head lane&7
  wave_lds_fence();                       // own-wave LDS only: no __syncthreads
  // ---- phase 2: wide gather ----
  int eg = lane >> 4, cb = lane & 15;
  int hq = cb >> 1;                       // head owning channels cb*8..cb*8+7
  float invh = __shfl(inv, hq, 64);
  float acc[8];
  #pragma unroll
  for (int k = 0; k < 8; k++) acc[k] = 0.f;
  int degc = deg < CAP ? deg : CAP;
  int j = 0;
  for (; j + 3 < degc; j += 4){
    int e = j + eg;
    int s = cs[e];
    float w = (float)es[e*8 + hq] * invh;
    half8 v = *(const half8*)(h1 + (size_t)s*128 + cb*8);
    #pragma unroll
    for (int k = 0; k < 8; k++) acc[k] += w*(float)v[k];
  }
  if (j < degc){                          // tail (predicated, <=3 edges)
    int e = j + eg;
    if (e < degc){
      int s = cs[e];
      float w = (float)es[e*8 + hq] * invh;
      half8 v = *(const half8*)(h1 + (size_t)s*128 + cb*8);
      #pragma unroll
      for (int k = 0; k < 8; k++) acc[k] += w*(float)v[k];
    }
  }
  for (int jj = degc; jj < deg; jj += 4){ // rare: deg > CAP, weights from ew1
    int e = jj + eg;
    if (e < deg){
      int s = col[beg + e];
      float w = (float)ewr[e*8 + hq] * invh;
      half8 v = *(const half8*)(h1 + (size_t)s*128 + cb*8);
      #pragma unroll
      for (int k = 0; k < 8; k++) acc[k] += w*(float)v[k];
    }
  }
  // cross-eg reduce (4 edge groups)
  #pragma unroll
  for (int k = 0; k < 8; k++){
    acc[k] += __shfl_xor(acc[k], 16, 64);
    acc[k] += __shfl_xor(acc[k], 32, 64);
  }
  // bias + ReLU; lanes eg==0 write the full row (16 lanes x 16B, coalesced)
  float4 b0 = *(const float4*)(bias + cb*8);
  float4 b1 = *(const float4*)(bias + cb*8 + 4);
  float bb[8] = {b0.x,b0.y,b0.z,b0.w,b1.x,b1.y,b1.z,b1.w};
  half8 oh;
  #pragma unroll
  for (int k = 0; k < 8; k++) oh[k] = (_Float16)fmaxf(acc[k] + bb[k], 0.f);
  if (eg == 0){
    *(half8*)(hr + (size_t)n*128 + cb*8) = oh;
    ((half8*)&ot_s[wv][0])[cb] = oh;      // same-wave LDS transpose staging
  }
  wave_lds_fence();
  // fused alpha2: lane -> (head hh=lane>>3, segment seg=lane&7)
  int hh = lane >> 3, seg = lane & 7;
  const half2v* otp = (const half2v*)&ot_s[wv][0];
  const float* wsr = ws2 + hh*128 + seg*16;
  const float* wdr = wd2 + hh*128 + seg*16;
  float vs = 0.f, vd = 0.f;
  #pragma unroll
  for (int i = 0; i < 8; i++){
    half2v v = otp[seg*8 + i];
    float vx = (float)v.x, vy = (float)v.y;
    vs += vx*wsr[2*i] + vy*wsr[2*i + 1];
    vd += vx*wdr[2*i] + vy*wdr[2*i + 1];
  }
  vs += __shfl_xor(vs, 1, 64); vd += __shfl_xor(vd, 1, 64);
  vs += __shfl_xor(vs, 2, 64); vd += __shfl_xor(vd, 2, 64);
  vs += __shfl_xor(vs, 4, 64); vd += __shfl_xor(vd, 4, 64);
  if (seg == 0){
    als2[n*8 + hh] = vs;
    ald2[n*8 + hh] = vd;
  }
}

// ===== layer 2 FUSED: softmax+agg (16 waves = 16 nodes) + output MFMA GEMM =====
// R10 measured-best form: two-phase LDS exp table, (hp,cb) gather with 2-stage
// software pipeline (8 gathers in flight), one __syncthreads before MFMA.
__global__ void __launch_bounds__(1024) k_attn_agg2(const _Float16* __restrict__ hr,
    const float* __restrict__ als, const float* __restrict__ ald,
    const int* __restrict__ row_ptr, const int* __restrict__ col,
    const _Float16* __restrict__ Bp, const float* __restrict__ b2,
    float* __restrict__ outp){
  __shared__ _Float16 ew_s[16][CAP*8];
  __shared__ int col_s[16][CAP];
  __shared__ _Float16 at[16*LRS];
  int tid = threadIdx.x;
  int wv = tid >> 6, lane = tid & 63;
  int n = blockIdx.x*16 + wv;             // grid exact: 3125*16 = 50000
  int beg = row_ptr[n], end = row_ptr[n+1];
  int deg = end - beg;
  int items = deg*8;
  int h = lane & 7;
  float ad = ald[n*8 + h];
  _Float16* es = ew_s[wv];
  int* cs = col_s[wv];
  float l = 0.f;
  int itc = items < CAP*8 ? items : CAP*8;
  int it = lane;
  for (; it < itc; it += 64){
    int e = it >> 3;
    int s = col[beg + e];
    float a = als[s*8 + h] + ad;
    a = (a > 0.f) ? a : 0.2f*a;
    float ex = __expf(a);
    es[it] = (_Float16)ex;
    if ((it & 7) == 0) cs[e] = s;
    l += ex;
  }
  for (; it < items; it += 64){
    int s = col[beg + (it >> 3)];
    float a = als[s*8 + h] + ad;
    a = (a > 0.f) ? a : 0.2f*a;
    l += __expf(a);
  }
  l += __shfl_xor(l, 8, 64);
  l += __shfl_xor(l, 16, 64);
  l += __shfl_xor(l, 32, 64);
  float inv = 1.f / (l + 1e-16f);   // for head lane&7 (lanes with same lane&7 agree)
  wave_lds_fence();                 // own-wave LDS only: no cross-wave barrier here
  int hp = lane >> 4, cb = lane & 15;
  float invA = __shfl(inv, 2*hp, 64);       // inv for head 2hp   (held by lane 2hp)
  float invB = __shfl(inv, 2*hp + 1, 64);   // inv for head 2hp+1
  half2v inv2; inv2.x = (_Float16)invA; inv2.y = (_Float16)invB;
  half2v acc_a[4], acc_b[4];
  #pragma unroll
  for (int i = 0; i < 4; i++){
    acc_a[i] = (half2v){(_Float16)0.f, (_Float16)0.f};
    acc_b[i] = (half2v){(_Float16)0.f, (_Float16)0.f};
  }
  int degc = deg < CAP ? deg : CAP;
  const _Float16* esw = es + 2*hp;          // per-lane weight base (both heads, u32)
  int j = 0;
  half8 cv0, cv1, cv2, cv3;
  if (j + 3 < degc){                        // prologue: load group 0
    cv0 = *(const half8*)(hr + (size_t)cs[j+0]*128 + cb*8);
    cv1 = *(const half8*)(hr + (size_t)cs[j+1]*128 + cb*8);
    cv2 = *(const half8*)(hr + (size_t)cs[j+2]*128 + cb*8);
    cv3 = *(const half8*)(hr + (size_t)cs[j+3]*128 + cb*8);
  }
  for (; j + 7 < degc; j += 4){
    // issue NEXT group's gathers first (hides L2/L3 latency under the FMAs)
    half8 nv0 = *(const half8*)(hr + (size_t)cs[j+4]*128 + cb*8);
    half8 nv1 = *(const half8*)(hr + (size_t)cs[j+5]*128 + cb*8);
    half8 nv2 = *(const half8*)(hr + (size_t)cs[j+6]*128 + cb*8);
    half8 nv3 = *(const half8*)(hr + (size_t)cs[j+7]*128 + cb*8);
    half2v w0 = *(const half2v*)(esw + (j+0)*8) * inv2;
    half2v w1 = *(const half2v*)(esw + (j+1)*8) * inv2;
    half2v w2 = *(const half2v*)(esw + (j+2)*8) * inv2;
    half2v w3 = *(const half2v*)(esw + (j+3)*8) * inv2;
    #pragma unroll
    for (int k = 0; k < 4; k++){
      half2v t;
      t = (half2v){cv0[2*k], cv0[2*k+1]};
      acc_a[k] += (half2v){w0.x, w0.x} * t;
      acc_b[k] += (half2v){w0.y, w0.y} * t;
      t = (half2v){cv1[2*k], cv1[2*k+1]};
      acc_a[k] += (half2v){w1.x, w1.x} * t;
      acc_b[k] += (half2v){w1.y, w1.y} * t;
      t = (half2v){cv2[2*k], cv2[2*k+1]};
      acc_a[k] += (half2v){w2.x, w2.x} * t;
      acc_b[k] += (half2v){w2.y, w2.y} * t;
      t = (half2v){cv3[2*k], cv3[2*k+1]};
      acc_a[k] += (half2v){w3.x, w3.x} * t;
      acc_b[k] += (half2v){w3.y, w3.y} * t;
    }
    cv0 = nv0; cv1 = nv1; cv2 = nv2; cv3 = nv3;
  }
  if (j + 3 < degc){                        // epilogue: consume last full group
    half2v w0 = *(const half2v*)(esw + (j+0)*8) * inv2;
    half2v w1 = *(const half2v*)(esw + (j+1)*8) * inv2;
    half2v w2 = *(const half2v*)(esw + (j+2)*8) * inv2;
    half2v w3 = *(const half2v*)(esw + (j+3)*8) * inv2;
    #pragma unroll
    for (int k = 0; k < 4; k++){
      half2v t;
      t = (half2v){cv0[2*k], cv0[2*k+1]};
      acc_a[k] += (half2v){w0.x, w0.x} * t;
      acc_b[k] += (half2v){w0.y, w0.y} * t;
      t = (half2v){cv1[2*k], cv1[2*k+1]};
      acc_a[k] += (half2v){w1.x, w1.x} * t;
      acc_b[k] += (half2v){w1.y, w1.y} * t;
      t = (half2v){cv2[2*k], cv2[2*k+1]};
      acc_a[k] += (half2v){w2.x, w2.x} * t;
      acc_b[k] += (half2v){w2.y, w2.y} * t;
      t = (half2v){cv3[2*k], cv3[2*k+1]};
      acc_a[k] += (half2v){w3.x, w3.x} * t;
      acc_b[k] += (half2v){w3.y, w3.y} * t;
    }
    j += 4;
  }
  for (; j < degc; j++){
    int s = cs[j];
    half2v w = *(const half2v*)(esw + j*8) * inv2;
    half8 v = *(const half8*)(hr + (size_t)s*128 + cb*8);
    #pragma unroll
    for (int k = 0; k < 4; k++){
      half2v t = (half2v){v[2*k], v[2*k+1]};
      acc_a[k] += (half2v){w.x, w.x} * t;
      acc_b[k] += (half2v){w.y, w.y} * t;
    }
  }
  if (deg > CAP){                             // rare: deg > CAP, recompute weights
    float2 adv = *(const float2*)(ald + (size_t)n*8 + 2*hp);
    for (; j < deg; j++){
      int s = col[beg + j];
      float2 alv = *(const float2*)(als + (size_t)s*8 + 2*hp);
      float a0 = alv.x + adv.x; a0 = (a0 > 0.f) ? a0 : 0.2f*a0;
      float a1 = alv.y + adv.y; a1 = (a1 > 0.f) ? a1 : 0.2f*a1;
      _Float16 w0 = (_Float16)(__expf(a0)*invA);
      _Float16 w1 = (_Float16)(__expf(a1)*invB);
      half8 v = *(const half8*)(hr + (size_t)s*128 + cb*8);
      #pragma unroll
      for (int k = 0; k < 4; k++){
        half2v t = (half2v){v[2*k], v[2*k+1]};
        acc_a[k] += (half2v){w0, w0} * t;
        acc_b[k] += (half2v){w1, w1} * t;
      }
    }
  }
  // write normalized rows into the LDS A-tile: head 2hp and 2hp+1, channels cb*8..
  _Float16* ar = at + wv*LRS + (2*hp)*128 + cb*8;
  half8 oa, ob;
  #pragma unroll
  for (int k = 0; k < 4; k++){
    oa[2*k] = acc_a[k].x; oa[2*k+1] = acc_a[k].y;
    ob[2*k] = acc_b[k].x; ob[2*k+1] = acc_b[k].y;
  }
  *(half8*)ar = oa;
  *(half8*)(ar + 128) = ob;
  __syncthreads();
  if (wv >= 4) return;
  // MFMA epilogue: wave wv = output col-tile nt; A from LDS, Bp L2-hot
  int m = lane & 15, q = lane >> 4;
  const _Float16* arow = at + m*LRS + q*8;
  f32x4 cacc = (f32x4){0.f,0.f,0.f,0.f};
  #pragma unroll 4
  for (int kt = 0; kt < 32; kt++){
    half8 af = *(const half8*)(arow + kt*32);
    half8 bf = *(const half8*)(Bp + (((kt*4 + wv)*64 + lane) << 3));
    cacc = __builtin_amdgcn_mfma_f32_16x16x32_f16(af, bf, cacc, 0, 0, 0);
  }
  int c = wv*16 + m;
  float bb = b2[c];
  #pragma unroll
  for (int r = 0; r < 4; r++){
    int nrow = blockIdx.x*16 + q*4 + r;   // C/D: col=lane&15, row=(lane>>4)*4+reg [m89]
    outp[(size_t)nrow*64 + c] = cacc[r] + bb;
  }
}

extern "C" void kernel_launch(void* const* d_in, const int* in_sizes, int n_in,
                              void* d_out, int out_size, void* d_ws, size_t ws_size,
                              hipStream_t stream){
  const float* x   = (const float*)d_in[0];
  const int*   ei  = (const int*)d_in[1];
  const float* W1  = (const float*)d_in[2];
  const float* as1 = (const float*)d_in[3];
  const float* ad1 = (const float*)d_in[4];
  const float* b1  = (const float*)d_in[5];
  const float* W2  = (const float*)d_in[6];
  const float* as2 = (const float*)d_in[7];
  const float* ad2 = (const float*)d_in[8];
  const float* b2  = (const float*)d_in[9];
  float* outp = (float*)d_out;

  char* p = (char*)d_ws;
  auto alloc = [&](size_t bytes) -> void* {
    void* r = (void*)p;
    p += (bytes + 255) & ~(size_t)255;
    return r;
  };
  _Float16* h1  = (_Float16*)alloc((size_t)NPAD*128*2);          // [N,128] fp16
  _Float16* hr  = (_Float16*)alloc((size_t)N_NODES*128*2);       // [N,128] fp16
  _Float16* ew1 = (_Float16*)alloc((size_t)ET*8*2);              // layer-1 edge weights
  float* als1 = (float*)alloc((size_t)N_NODES*8*4);
  float* ald1 = (float*)alloc((size_t)N_NODES*8*4);
  float* als2 = (float*)alloc((size_t)N_NODES*8*4);
  float* ald2 = (float*)alloc((size_t)N_NODES*8*4);
  int* row_ptr = (int*)alloc((size_t)(N_NODES+1)*4);
  int* deg  = (int*)alloc((size_t)N_NODES*4);
  int* cnt  = (int*)alloc((size_t)N_NODES*4);
  int* col  = (int*)alloc((size_t)ET*4);
  int* loc  = (int*)alloc((size_t)N_NODES*4);
  int* part = (int*)alloc(256*4);
  int* carry= (int*)alloc(256*4);
  int* flag = (int*)alloc(256);
  float* ws2 = (float*)alloc(1024*4);
  float* wd2 = (float*)alloc(1024*4);
  _Float16* Bp1 = (_Float16*)alloc((size_t)16384*2);
  _Float16* Bp  = (_Float16*)alloc((size_t)65536*2);

  dim3 b256(256);
  // launch 1: init + weight prep (independent block ranges)
  k_init_wprep<<<SCAN_NB + 324, b256, 0, stream>>>(ei, deg, cnt, flag,
                                                   W1, W2, as2, ad2,
                                                   Bp1, Bp, ws2, wd2);
  // launch 2: degree atomics || layer-1 GEMM (independent, overlapped)
  k_deg_gemm1<<<NB_DEG + NB_GEMM1, b256, 0, stream>>>(ei, deg, flag,
                                                      x, Bp1, h1, as1, ad1,
                                                      als1, ald1);
  // CSR scan
  k_scan_part<<<SCAN_NB, b256, 0, stream>>>(deg, loc, part);
  k_scan_carry<<<1, b256, 0, stream>>>(part, carry);
  k_scan_add<<<SCAN_NB, b256, 0, stream>>>(loc, carry, row_ptr);
  // CSR fill + layer-1 edge-weight precompute
  k_fill<<<(ET+255)/256, b256, 0, stream>>>(ei, row_ptr, cnt, col, flag,
                                            als1, ald1, ew1);
  // layer 1 softmax+agg (phase 1 reads precomputed ew1; alpha2 fused)
  k_attn_agg1<<<N_NODES/4, b256, 0, stream>>>(h1, ew1, row_ptr, col,
                                              b1, hr, ws2, wd2, als2, ald2);
  // layer 2: fused softmax+agg+output-GEMM
  k_attn_agg2<<<N_NODES/16, dim3(1024), 0, stream>>>(hr, als2, ald2, row_ptr, col,
                                                     Bp, b2, outp);
}